// Round 10
// baseline (1071.122 us; speedup 1.0000x reference)
//
#include <hip/hip_runtime.h>
#include <hip/hip_bf16.h>

#define HID 64
#define MSG 128
#define NDIM 32
#define EDIM 16
#define NG 512
#define SCAP 192

typedef unsigned short u16;
typedef unsigned int u32;
typedef _Float16 h8 __attribute__((ext_vector_type(8)));
typedef _Float16 h4 __attribute__((ext_vector_type(4)));
typedef _Float16 h2 __attribute__((ext_vector_type(2)));

__device__ __forceinline__ float sigm(float x){return 1.0f/(1.0f+expf(-x));}
__device__ __forceinline__ int rfl(int x){return __builtin_amdgcn_readfirstlane(x);}
__device__ __forceinline__ u32 pkh(float a, float b){
    union { h2 h; u32 u; } v; v.h[0] = (_Float16)a; v.h[1] = (_Float16)b; return v.u;
}
__device__ __forceinline__ h2 pk2h(float a, float b){
    union { __fp16 __attribute__((ext_vector_type(2))) r; h2 h; } v;
    v.r = __builtin_amdgcn_cvt_pkrtz(a, b);
    return v.h;
}
__device__ __forceinline__ float fdot2_(h2 a, u32 w, float c){
    union { u32 u; h2 h; } v; v.u = w;
    return __builtin_amdgcn_fdot2(a, v.h, c, false);
}

// ---------------- CSR build ----------------
__global__ void k_hist(const int* __restrict__ idx, int n, int* __restrict__ cnt) {
    int i = blockIdx.x * blockDim.x + threadIdx.x;
    int stride = gridDim.x * blockDim.x;
    for (; i < n; i += stride) atomicAdd(&cnt[idx[i]], 1);
}

__global__ void k_scanA(const int* __restrict__ in, int* __restrict__ out,
                        int* __restrict__ bsum, int n) {
    __shared__ int sh[1024];
    int i = blockIdx.x * 1024 + threadIdx.x;
    int v = (i < n) ? in[i] : 0;
    sh[threadIdx.x] = v;
    __syncthreads();
    for (int off = 1; off < 1024; off <<= 1) {
        int t = (threadIdx.x >= off) ? sh[threadIdx.x - off] : 0;
        __syncthreads();
        sh[threadIdx.x] += t;
        __syncthreads();
    }
    if (i < n) out[i] = sh[threadIdx.x] - v;
    if (threadIdx.x == 1023) bsum[blockIdx.x] = sh[1023];
}
__global__ void k_scanB(const int* __restrict__ bsum, int* __restrict__ boff, int nb) {
    if (threadIdx.x == 0) {
        int r = 0;
        for (int b = 0; b < nb; b++) { boff[b] = r; r += bsum[b]; }
        boff[nb] = r;
    }
}
__global__ void k_scanC(int* __restrict__ out, const int* __restrict__ boff, int n, int nb) {
    int i = blockIdx.x * blockDim.x + threadIdx.x;
    if (i < n) out[i] += boff[i >> 10];
    else if (i == n) out[n] = boff[nb];
}

__global__ void k_gptr(const int* __restrict__ batch, int N, int* __restrict__ gptr) {
    int g = blockIdx.x * blockDim.x + threadIdx.x;
    if (g > NG) return;
    int lo = 0, hi = N;
    while (lo < hi) { int mid = (lo + hi) >> 1; if (batch[mid] < g) lo = mid + 1; else hi = mid; }
    gptr[g] = lo;
}

__global__ void k_scatter(const int* __restrict__ src, const int* __restrict__ dst, int n,
                          const int* __restrict__ ptr, int* __restrict__ cursor,
                          int* __restrict__ eidx, int* __restrict__ slist) {
    int i = blockIdx.x * blockDim.x + threadIdx.x;
    int stride = gridDim.x * blockDim.x;
    for (; i < n; i += stride) {
        int d = dst[i];
        int pos = ptr[d] + atomicAdd(&cursor[d], 1);
        eidx[pos] = i;
        slist[pos] = src[i];
    }
}

// permute edge_attr into CSR order, fp16
__global__ void k_permea(const int* __restrict__ eidx, const float* __restrict__ ea,
                         _Float16* __restrict__ eap, int E) {
    int i = blockIdx.x * blockDim.x + threadIdx.x;
    if (i >= E) return;
    int e = eidx[i];
    const float* s = ea + (size_t)e * EDIM;
    float4 a = *(const float4*)s, b = *(const float4*)(s + 4);
    float4 c = *(const float4*)(s + 8), d = *(const float4*)(s + 12);
    h8 o0, o1;
    o0[0]=(_Float16)a.x; o0[1]=(_Float16)a.y; o0[2]=(_Float16)a.z; o0[3]=(_Float16)a.w;
    o0[4]=(_Float16)b.x; o0[5]=(_Float16)b.y; o0[6]=(_Float16)b.z; o0[7]=(_Float16)b.w;
    o1[0]=(_Float16)c.x; o1[1]=(_Float16)c.y; o1[2]=(_Float16)c.z; o1[3]=(_Float16)c.w;
    o1[4]=(_Float16)d.x; o1[5]=(_Float16)d.y; o1[6]=(_Float16)d.z; o1[7]=(_Float16)d.w;
    h8* dp = (h8*)(eap + (size_t)i * EDIM);
    dp[0] = o0; dp[1] = o1;
}

// ---------------- fuse W2 into GRU input gates: G = W2 @ Wih_gate^T, gb = Wih_gate @ b2 ----------------
// Layouts (per (k4, c)): GA = {r01,z01,n01,r23}, GB = {z23,n23}; same for U (Whh transpose-pack).
__global__ void k_fuse(const float* __restrict__ Wih, const float* __restrict__ Whh,
                       const float* __restrict__ W2, const float* __restrict__ bm2,
                       uint4* __restrict__ gGA, uint2* __restrict__ gGB,
                       uint4* __restrict__ gUA, uint2* __restrict__ gUB,
                       float* __restrict__ gbb) {
    int t = blockIdx.x * blockDim.x + threadIdx.x;
    if (t < 2048) {            // H-side fused weights: k4 in [0,32), c in [0,64)
        int k4 = t >> 6, c = t & 63;
        float G[3][4];
#pragma unroll
        for (int g = 0; g < 3; g++)
#pragma unroll
            for (int kk = 0; kk < 4; kk++) {
                int j = 4 * k4 + kk;
                const float* w2r = W2 + (size_t)j * 64;
                const float* wir = Wih + (size_t)(g * 64 + c) * 64;
                float s = 0.f;
                for (int k = 0; k < 64; k++) s += w2r[k] * wir[k];
                G[g][kk] = s;
            }
        uint4 A; uint2 B;
        A.x = pkh(G[0][0], G[0][1]); A.y = pkh(G[1][0], G[1][1]);
        A.z = pkh(G[2][0], G[2][1]); A.w = pkh(G[0][2], G[0][3]);
        B.x = pkh(G[1][2], G[1][3]); B.y = pkh(G[2][2], G[2][3]);
        gGA[t] = A; gGB[t] = B;
    } else if (t < 3072) {     // U (hidden-side) transpose pack: k4 in [0,16)
        int u = t - 2048;
        int k4 = u >> 6, c = u & 63;
        float U[3][4];
#pragma unroll
        for (int g = 0; g < 3; g++)
#pragma unroll
            for (int kk = 0; kk < 4; kk++)
                U[g][kk] = Whh[(size_t)(g * 64 + c) * 64 + 4 * k4 + kk];
        uint4 A; uint2 B;
        A.x = pkh(U[0][0], U[0][1]); A.y = pkh(U[1][0], U[1][1]);
        A.z = pkh(U[2][0], U[2][1]); A.w = pkh(U[0][2], U[0][3]);
        B.x = pkh(U[1][2], U[1][3]); B.y = pkh(U[2][2], U[2][3]);
        gUA[u] = A; gUB[u] = B;
    } else if (t < 3072 + 192) {  // gb[g*64+c] = sum_k b2[k] * Wih[g*64+c][k]
        int cg = t - 3072;
        const float* wir = Wih + (size_t)cg * 64;
        float s = 0.f;
        for (int k = 0; k < 64; k++) s += bm2[k] * wir[k];
        gbb[cg] = s;
    }
}

// ---------------- LSTM weight transpose (coalesced reads in k_s2s) ----------------
__global__ void k_packl(const float* __restrict__ lWih, const float* __restrict__ lWhh,
                        float* __restrict__ WT1, float* __restrict__ WT2) {
    int t = blockIdx.x * blockDim.x + threadIdx.x;
    if (t < 256 * 128) { int g = t >> 7, k = t & 127; WT1[k * 256 + g] = lWih[g * 128 + k]; }
    if (t < 256 * 64)  { int g = t >> 6, k = t & 63;  WT2[k * 256 + g] = lWhh[g * 64 + k]; }
}

// ---------------- node embedding ----------------
__global__ void k_embed(const float* __restrict__ xf, const float* __restrict__ We,
                        const float* __restrict__ be, float* __restrict__ xh, int N) {
    __shared__ float Wl[NDIM * HID];
    for (int t = threadIdx.x; t < NDIM * HID; t += blockDim.x) Wl[t] = We[t];
    __syncthreads();
    int total = N * HID;
    int stride = gridDim.x * blockDim.x;
    for (int idx = blockIdx.x * blockDim.x + threadIdx.x; idx < total; idx += stride) {
        int n = idx >> 6, c = idx & 63;
        const float* xr = xf + n * NDIM;
        float acc = be[c];
#pragma unroll
        for (int k = 0; k < NDIM; k++) acc += xr[k] * Wl[k * HID + c];
        xh[idx] = acc;
    }
}

// ---------------- k_prep: Pd (-> Hb, f32) and Ps (f16) ----------------
__global__ void __launch_bounds__(256)
k_prep(const float* __restrict__ xh, const float* __restrict__ Wm1,
       const float* __restrict__ bm1, float* __restrict__ Hb,
       _Float16* __restrict__ PsH, int N) {
    __shared__ float Wl[64 * 256];
    for (int t = threadIdx.x; t < 64 * 256; t += 256) {
        int k = t >> 8, cc = t & 255;
        Wl[t] = (cc < 128) ? Wm1[k * 128 + cc] : Wm1[(64 + k) * 128 + (cc - 128)];
    }
    __syncthreads();
    int wv = threadIdx.x >> 6, lane = threadIdx.x & 63;
    int cc = lane * 4;
    float4 bias;
    if (lane < 32) bias = *(const float4*)&bm1[cc];
    else bias = make_float4(0.f, 0.f, 0.f, 0.f);
    int ngroups = (N + 7) >> 3;
    for (int g = blockIdx.x * 4 + wv; g < ngroups; g += gridDim.x * 4) {
        int base = rfl(g) * 8;
        const float* xp[8];
#pragma unroll
        for (int t = 0; t < 8; t++) {
            int d = base + t; if (d > N - 1) d = N - 1;
            xp[t] = xh + (size_t)d * 64;
        }
        float4 acc[8];
#pragma unroll
        for (int t = 0; t < 8; t++) acc[t] = bias;
#pragma unroll 2
        for (int k4 = 0; k4 < 16; k4++) {
            int k = k4 * 4;
            float4 xv4[8];
#pragma unroll
            for (int t = 0; t < 8; t++) xv4[t] = *(const float4*)&xp[t][k];
#pragma unroll
            for (int kk = 0; kk < 4; kk++) {
                float4 w = *(const float4*)&Wl[(k + kk) * 256 + cc];
#pragma unroll
                for (int t = 0; t < 8; t++) {
                    float xv = kk == 0 ? xv4[t].x : kk == 1 ? xv4[t].y : kk == 2 ? xv4[t].z : xv4[t].w;
                    acc[t].x += xv * w.x; acc[t].y += xv * w.y;
                    acc[t].z += xv * w.z; acc[t].w += xv * w.w;
                }
            }
        }
#pragma unroll
        for (int t = 0; t < 8; t++) {
            int d = base + t;
            if (d < N) {
                if (lane < 32) *(float4*)&Hb[(size_t)d * 128 + cc] = acc[t];
                else {
                    h4 o;
                    o[0] = (_Float16)acc[t].x; o[1] = (_Float16)acc[t].y;
                    o[2] = (_Float16)acc[t].z; o[3] = (_Float16)acc[t].w;
                    *(h4*)&PsH[(size_t)d * 128 + (cc - 128)] = o;
                }
            }
        }
    }
}

// ---------------- k_edge: fdot2 inner product ----------------
__global__ void __launch_bounds__(256)
k_edge(const _Float16* __restrict__ PsH, const _Float16* __restrict__ eap,
       const float* __restrict__ Wm1, const int* __restrict__ ptr,
       const int* __restrict__ slist, float* __restrict__ Hb, int N) {
    int c = threadIdx.x & 127;
    int half = threadIdx.x >> 7;
    h2 wh[8];
#pragma unroll
    for (int k = 0; k < 8; k++) {
        h2 t;
        t[0] = (_Float16)Wm1[128 * 128 + (2 * k) * 128 + c];
        t[1] = (_Float16)Wm1[128 * 128 + (2 * k + 1) * 128 + c];
        wh[k] = t;
    }
    for (int dd = blockIdx.x * 2 + half; dd < N; dd += gridDim.x * 2) {
        int d = rfl(dd);
        float pd = Hb[(size_t)d * 128 + c];
        int eb = rfl(ptr[d]), ee = rfl(ptr[d + 1]);
        const int* sp = slist + eb;
        const _Float16* ep = eap + (size_t)eb * EDIM;
        int ne = ee - eb;
        float acc = 0.f;
        int i = 0;
        for (; i + 8 <= ne; i += 8) {
            int ns[8];
#pragma unroll
            for (int j = 0; j < 8; j++) ns[j] = rfl(sp[i + j]);
            float pv[8];
#pragma unroll
            for (int j = 0; j < 8; j++) pv[j] = (float)PsH[(size_t)ns[j] * 128 + c];
#pragma unroll
            for (int j = 0; j < 8; j++) {
                union { uint4 u; h2 h[4]; } A, B;
                A.u = *(const uint4*)(ep + (size_t)(i + j) * EDIM);
                B.u = *(const uint4*)(ep + (size_t)(i + j) * EDIM + 8);
                float pe = 0.f;
#pragma unroll
                for (int k = 0; k < 4; k++) pe = __builtin_amdgcn_fdot2(A.h[k], wh[k], pe, false);
#pragma unroll
                for (int k = 0; k < 4; k++) pe = __builtin_amdgcn_fdot2(B.h[k], wh[4 + k], pe, false);
                acc += fmaxf(pd + pv[j] + pe, 0.f);
            }
        }
        for (; i < ne; i++) {
            int n0 = rfl(sp[i]);
            float pv = (float)PsH[(size_t)n0 * 128 + c];
            union { uint4 u; h2 h[4]; } A, B;
            A.u = *(const uint4*)(ep + (size_t)i * EDIM);
            B.u = *(const uint4*)(ep + (size_t)i * EDIM + 8);
            float pe = 0.f;
#pragma unroll
            for (int k = 0; k < 4; k++) pe = __builtin_amdgcn_fdot2(A.h[k], wh[k], pe, false);
#pragma unroll
            for (int k = 0; k < 4; k++) pe = __builtin_amdgcn_fdot2(B.h[k], wh[4 + k], pe, false);
            acc += fmaxf(pd + pv + pe, 0.f);
        }
        Hb[(size_t)d * 128 + c] = acc;
    }
}

// ---------------- k_node: fused (msg @ W2 folded) GRU. wave per node, fp16 fdot2 ----------------
__global__ void __launch_bounds__(256)
k_node(const float* __restrict__ H, const uint4* __restrict__ gGA, const uint2* __restrict__ gGB,
       const uint4* __restrict__ gUA, const uint2* __restrict__ gUB,
       const float* __restrict__ gbb, const float* __restrict__ bih, const float* __restrict__ bhh,
       const int* __restrict__ ptr, const float* __restrict__ xin, float* __restrict__ xout, int N) {
    extern __shared__ char smem[];
    uint4* GA = (uint4*)smem;              // 32 KB
    uint2* GB = (uint2*)(smem + 32768);    // 16 KB
    uint4* UA = (uint4*)(smem + 49152);    // 16 KB
    uint2* UB = (uint2*)(smem + 65536);    //  8 KB
    for (int t = threadIdx.x; t < 2048; t += 256) { GA[t] = gGA[t]; GB[t] = gGB[t]; }
    for (int t = threadIdx.x; t < 1024; t += 256) { UA[t] = gUA[t]; UB[t] = gUB[t]; }
    __syncthreads();
    int wv = threadIdx.x >> 6, lane = threadIdx.x & 63;
    float gbr = gbb[lane], gbz = gbb[64 + lane], gbn = gbb[128 + lane];
    float br = bih[lane], bz = bih[64 + lane], bn = bih[128 + lane];
    float cr = bhh[lane], cz = bhh[64 + lane], cn = bhh[128 + lane];
    for (int dd = blockIdx.x * 4 + wv; dd < N; dd += gridDim.x * 4) {
        int d = rfl(dd);
        const float* hp = H + (size_t)d * 128;
        const float* xp = xin + (size_t)d * 64;
        float hv = xp[lane];
        float deg = (float)(ptr[d + 1] - ptr[d]);
        float gr = br + deg * gbr, gz = bz + deg * gbz, gn = bn + deg * gbn;
#pragma unroll 2
        for (int k4 = 0; k4 < 32; k4++) {
            float4 hx = *(const float4*)&hp[k4 * 4];
            h2 a01 = pk2h(hx.x, hx.y), a23 = pk2h(hx.z, hx.w);
            uint4 wa = GA[k4 * 64 + lane];
            uint2 wb = GB[k4 * 64 + lane];
            gr = fdot2_(a01, wa.x, gr); gz = fdot2_(a01, wa.y, gz); gn = fdot2_(a01, wa.z, gn);
            gr = fdot2_(a23, wa.w, gr); gz = fdot2_(a23, wb.x, gz); gn = fdot2_(a23, wb.y, gn);
        }
        float hr_ = cr, hz_ = cz, hn_ = cn;
#pragma unroll 2
        for (int k4 = 0; k4 < 16; k4++) {
            float4 hx = *(const float4*)&xp[k4 * 4];
            h2 a01 = pk2h(hx.x, hx.y), a23 = pk2h(hx.z, hx.w);
            uint4 wa = UA[k4 * 64 + lane];
            uint2 wb = UB[k4 * 64 + lane];
            hr_ = fdot2_(a01, wa.x, hr_); hz_ = fdot2_(a01, wa.y, hz_); hn_ = fdot2_(a01, wa.z, hn_);
            hr_ = fdot2_(a23, wa.w, hr_); hz_ = fdot2_(a23, wb.x, hz_); hn_ = fdot2_(a23, wb.y, hn_);
        }
        float r = sigm(gr + hr_);
        float z = sigm(gz + hz_);
        float nn = tanhf(gn + r * hn_);
        xout[(size_t)d * 64 + lane] = (1.f - z) * nn + z * hv;
    }
}

// ---------------- fused Set2Set ----------------
__global__ void __launch_bounds__(1024)
k_s2s(const float* __restrict__ xh, const int* __restrict__ gptr,
      const float* __restrict__ WT1, const float* __restrict__ WT2,
      const float* __restrict__ lbih, const float* __restrict__ lbhh,
      const float* __restrict__ Wr1, const float* __restrict__ br1,
      const float* __restrict__ Wr2, const float* __restrict__ br2,
      float* __restrict__ out) {
    int b = blockIdx.x, tid = threadIdx.x;
    __shared__ float xl[SCAP * 64];
    __shared__ float qs[128], qhl[64], qcs[64], g[256], red[16], asums[16], rvs[1024];
    int start = gptr[b], end = gptr[b + 1];
    int seg = end - start;
    bool uselds = (seg <= SCAP);
    if (uselds) {
        int tot = seg * 64;
        for (int t = tid; t < tot; t += 1024) xl[t] = xh[(size_t)start * 64 + t];
    }
    if (tid < 128) qs[tid] = 0.f;
    if (tid < 64) { qhl[tid] = 0.f; qcs[tid] = 0.f; }
    __syncthreads();
    int grp = tid >> 6, lane = tid & 63;
    int gate = tid & 255, part = tid >> 8;
    for (int s = 0; s < 6; s++) {
        {
            float acc = 0.f;
            int k0 = part * 32;
#pragma unroll 8
            for (int k = k0; k < k0 + 32; k++) acc += qs[k] * WT1[k * 256 + gate];
            int k1 = part * 16;
#pragma unroll 8
            for (int k = k1; k < k1 + 16; k++) acc += qhl[k] * WT2[k * 256 + gate];
            rvs[tid] = acc;
        }
        __syncthreads();
        if (tid < 256) g[tid] = lbih[tid] + lbhh[tid] + rvs[tid] + rvs[256 + tid] + rvs[512 + tid] + rvs[768 + tid];
        __syncthreads();
        if (tid < 64) {
            float ig = sigm(g[tid]), fg = sigm(g[64 + tid]);
            float gg = tanhf(g[128 + tid]), og = sigm(g[192 + tid]);
            float c = fg * qcs[tid] + ig * gg;
            float h = og * tanhf(c);
            qcs[tid] = c; qhl[tid] = h; qs[tid] = h;
        }
        __syncthreads();
        float qv = qhl[lane];
        float mloc = -3.4e38f, asl = 0.f, rv = 0.f;
        for (int n = grp; n < seg; n += 16) {
            float xv = uselds ? xl[n * 64 + lane] : xh[(size_t)(start + n) * 64 + lane];
            float p = xv * qv;
#pragma unroll
            for (int off = 32; off > 0; off >>= 1) p += __shfl_xor(p, off);
            float mnew = fmaxf(mloc, p);
            float corr = expf(mloc - mnew);
            float a = expf(p - mnew);
            asl = asl * corr + a;
            rv = rv * corr + a * xv;
            mloc = mnew;
        }
        if (lane == 0) red[grp] = mloc;
        __syncthreads();
        float gmax = red[0];
#pragma unroll
        for (int j = 1; j < 16; j++) gmax = fmaxf(gmax, red[j]);
        float sc = expf(mloc - gmax);
        rvs[tid] = rv * sc;
        if (lane == 0) asums[grp] = asl * sc;
        __syncthreads();
        if (tid < 64) {
            float rt = 0.f, at = 0.f;
#pragma unroll
            for (int j = 0; j < 16; j++) { rt += rvs[tid + 64 * j]; at += asums[j]; }
            qs[64 + tid] = (at > 0.f) ? rt / at : 0.f;
        }
        __syncthreads();
    }
    if (tid < 64) {
        float a2 = br1[tid];
#pragma unroll 8
        for (int k = 0; k < 128; k++) a2 += qs[k] * Wr1[k * 64 + tid];
        a2 = fmaxf(a2, 0.f);
        float v = a2 * Wr2[tid];
#pragma unroll
        for (int off = 32; off > 0; off >>= 1) v += __shfl_xor(v, off);
        if (tid == 0) out[b] = v + br2[0];
    }
}

extern "C" void kernel_launch(void* const* d_in, const int* in_sizes, int n_in,
                              void* d_out, int out_size, void* d_ws, size_t ws_size,
                              hipStream_t stream) {
    const float* x_feat = (const float*)d_in[0];
    const int*   ei     = (const int*)d_in[1];
    const float* eattr  = (const float*)d_in[2];
    const int*   batch  = (const int*)d_in[3];
    const float* W_emb  = (const float*)d_in[4];
    const float* b_emb  = (const float*)d_in[5];
    const float* W_m1   = (const float*)d_in[6];
    const float* b_m1   = (const float*)d_in[7];
    const float* W_m2   = (const float*)d_in[8];
    const float* b_m2   = (const float*)d_in[9];
    const float* gWih   = (const float*)d_in[10];
    const float* gWhh   = (const float*)d_in[11];
    const float* gbih   = (const float*)d_in[12];
    const float* gbhh   = (const float*)d_in[13];
    const float* lWih   = (const float*)d_in[14];
    const float* lWhh   = (const float*)d_in[15];
    const float* lbih   = (const float*)d_in[16];
    const float* lbhh   = (const float*)d_in[17];
    const float* Wr1    = (const float*)d_in[18];
    const float* br1    = (const float*)d_in[19];
    const float* Wr2    = (const float*)d_in[20];
    const float* br2    = (const float*)d_in[21];

    int N = in_sizes[0] / NDIM;   // 50000
    int E = in_sizes[1] / 2;      // 800000

    char* w = (char*)d_ws;
    auto alloc = [&](size_t b) { char* p = w; w += (b + 511) & ~(size_t)511; return p; };
    float*     xh    = (float*)alloc((size_t)N * 64 * 4);
    float*     xh2   = (float*)alloc((size_t)N * 64 * 4);
    _Float16*  PsH   = (_Float16*)alloc((size_t)N * 128 * 2);
    float*     Hb    = (float*)alloc((size_t)N * 128 * 4);
    int*       ptr   = (int*)alloc((size_t)(N + 1) * 4);
    int*       slist = (int*)alloc((size_t)E * 4);
    int*       eidx  = (int*)alloc((size_t)E * 4);
    _Float16*  eap   = (_Float16*)alloc((size_t)E * EDIM * 2);
    uint4*     gGA   = (uint4*)alloc((size_t)2048 * 16);
    uint2*     gGB   = (uint2*)alloc((size_t)2048 * 8);
    uint4*     gUA   = (uint4*)alloc((size_t)1024 * 16);
    uint2*     gUB   = (uint2*)alloc((size_t)1024 * 8);
    float*     gbb   = (float*)alloc((size_t)192 * 4);
    float*     WT1   = (float*)alloc((size_t)128 * 256 * 4);
    float*     WT2   = (float*)alloc((size_t)64 * 256 * 4);
    int*       gptr  = (int*)alloc((size_t)(NG + 1) * 4);
    int*       bsum  = (int*)alloc(128 * 4);
    int*       boff  = (int*)alloc(128 * 4);
    char* z0 = w;
    int*       cnt    = (int*)alloc((size_t)N * 4);
    int*       cursor = (int*)alloc((size_t)N * 4);
    char* z0e = w;

    hipMemsetAsync(z0, 0, (size_t)(z0e - z0), stream);

    hipError_t attr_err = hipFuncSetAttribute((const void*)k_node,
        hipFuncAttributeMaxDynamicSharedMemorySize, 73728);
    (void)attr_err;

    int NB = (N + 1023) / 1024;
    k_hist<<<1024, 256, 0, stream>>>(ei + E, E, cnt);
    k_scanA<<<NB, 1024, 0, stream>>>(cnt, ptr, bsum, N);
    k_scanB<<<1, 64, 0, stream>>>(bsum, boff, NB);
    k_scanC<<<(N + 256) / 256, 256, 0, stream>>>(ptr, boff, N, NB);
    k_gptr<<<3, 256, 0, stream>>>(batch, N, gptr);
    k_scatter<<<3125, 256, 0, stream>>>(ei, ei + E, E, ptr, cursor, eidx, slist);
    k_permea<<<(E + 255) / 256, 256, 0, stream>>>(eidx, eattr, eap, E);
    k_fuse<<<13, 256, 0, stream>>>(gWih, gWhh, W_m2, b_m2, gGA, gGB, gUA, gUB, gbb);
    k_packl<<<128, 256, 0, stream>>>(lWih, lWhh, WT1, WT2);

    k_embed<<<2048, 256, 0, stream>>>(x_feat, W_emb, b_emb, xh, N);

    float* xa = xh;
    float* xb = xh2;
    for (int r = 0; r < 3; r++) {
        k_prep<<<391, 256, 0, stream>>>(xa, W_m1, b_m1, Hb, PsH, N);
        k_edge<<<4096, 256, 0, stream>>>(PsH, eap, W_m1, ptr, slist, Hb, N);
        k_node<<<512, 256, 73728, stream>>>(Hb, gGA, gGB, gUA, gUB, gbb, gbih, gbhh,
                                            ptr, xa, xb, N);
        float* t = xa; xa = xb; xb = t;
    }
    k_s2s<<<NG, 1024, 0, stream>>>(xa, gptr, WT1, WT2, lbih, lbhh,
                                   Wr1, br1, Wr2, br2, (float*)d_out);
}

// Round 11
// 947.770 us; speedup vs baseline: 1.1301x; 1.1301x over previous
//
#include <hip/hip_runtime.h>
#include <hip/hip_bf16.h>

#define HID 64
#define MSG 128
#define NDIM 32
#define EDIM 16
#define NG 512
#define SCAP 192

typedef unsigned short u16;
typedef unsigned int u32;
typedef _Float16 h8 __attribute__((ext_vector_type(8)));
typedef _Float16 h4 __attribute__((ext_vector_type(4)));
typedef _Float16 h2 __attribute__((ext_vector_type(2)));

__device__ __forceinline__ float sigm(float x){return 1.0f/(1.0f+expf(-x));}
__device__ __forceinline__ int rfl(int x){return __builtin_amdgcn_readfirstlane(x);}
__device__ __forceinline__ u32 pkh(float a, float b){
    union { h2 h; u32 u; } v; v.h[0] = (_Float16)a; v.h[1] = (_Float16)b; return v.u;
}
__device__ __forceinline__ h2 pk2h(float a, float b){
    union { __fp16 __attribute__((ext_vector_type(2))) r; h2 h; } v;
    v.r = __builtin_amdgcn_cvt_pkrtz(a, b);
    return v.h;
}
__device__ __forceinline__ float fdot2_(h2 a, u32 w, float c){
    union { u32 u; h2 h; } v; v.u = w;
    return __builtin_amdgcn_fdot2(a, v.h, c, false);
}

// ---------------- CSR build ----------------
__global__ void k_hist(const int* __restrict__ idx, int n, int* __restrict__ cnt) {
    int i = blockIdx.x * blockDim.x + threadIdx.x;
    int stride = gridDim.x * blockDim.x;
    for (; i < n; i += stride) atomicAdd(&cnt[idx[i]], 1);
}

__global__ void k_scanA(const int* __restrict__ in, int* __restrict__ out,
                        int* __restrict__ bsum, int n) {
    __shared__ int sh[1024];
    int i = blockIdx.x * 1024 + threadIdx.x;
    int v = (i < n) ? in[i] : 0;
    sh[threadIdx.x] = v;
    __syncthreads();
    for (int off = 1; off < 1024; off <<= 1) {
        int t = (threadIdx.x >= off) ? sh[threadIdx.x - off] : 0;
        __syncthreads();
        sh[threadIdx.x] += t;
        __syncthreads();
    }
    if (i < n) out[i] = sh[threadIdx.x] - v;
    if (threadIdx.x == 1023) bsum[blockIdx.x] = sh[1023];
}
__global__ void k_scanB(const int* __restrict__ bsum, int* __restrict__ boff, int nb) {
    if (threadIdx.x == 0) {
        int r = 0;
        for (int b = 0; b < nb; b++) { boff[b] = r; r += bsum[b]; }
        boff[nb] = r;
    }
}
__global__ void k_scanC(int* __restrict__ out, const int* __restrict__ boff, int n, int nb) {
    int i = blockIdx.x * blockDim.x + threadIdx.x;
    if (i < n) out[i] += boff[i >> 10];
    else if (i == n) out[n] = boff[nb];
}

__global__ void k_gptr(const int* __restrict__ batch, int N, int* __restrict__ gptr) {
    int g = blockIdx.x * blockDim.x + threadIdx.x;
    if (g > NG) return;
    int lo = 0, hi = N;
    while (lo < hi) { int mid = (lo + hi) >> 1; if (batch[mid] < g) lo = mid + 1; else hi = mid; }
    gptr[g] = lo;
}

// scatter + edge_attr permute (fp16) fused: sequential ea read, scattered eap write
__global__ void k_scatter(const int* __restrict__ src, const int* __restrict__ dst,
                          const float* __restrict__ ea, int n,
                          const int* __restrict__ ptr, int* __restrict__ cursor,
                          int* __restrict__ slist, _Float16* __restrict__ eap) {
    int i = blockIdx.x * blockDim.x + threadIdx.x;
    int stride = gridDim.x * blockDim.x;
    for (; i < n; i += stride) {
        int d = dst[i];
        int pos = ptr[d] + atomicAdd(&cursor[d], 1);
        slist[pos] = src[i];
        const float* s = ea + (size_t)i * EDIM;
        float4 a = *(const float4*)s, b = *(const float4*)(s + 4);
        float4 c = *(const float4*)(s + 8), d4 = *(const float4*)(s + 12);
        h8 o0, o1;
        o0[0]=(_Float16)a.x; o0[1]=(_Float16)a.y; o0[2]=(_Float16)a.z; o0[3]=(_Float16)a.w;
        o0[4]=(_Float16)b.x; o0[5]=(_Float16)b.y; o0[6]=(_Float16)b.z; o0[7]=(_Float16)b.w;
        o1[0]=(_Float16)c.x; o1[1]=(_Float16)c.y; o1[2]=(_Float16)c.z; o1[3]=(_Float16)c.w;
        o1[4]=(_Float16)d4.x; o1[5]=(_Float16)d4.y; o1[6]=(_Float16)d4.z; o1[7]=(_Float16)d4.w;
        h8* dp = (h8*)(eap + (size_t)pos * EDIM);
        dp[0] = o0; dp[1] = o1;
    }
}

// ---------------- fuse W2 into GRU input gates: G = W2 @ Wih_gate^T, gb = Wih_gate @ b2 ----------------
__global__ void k_fuse(const float* __restrict__ Wih, const float* __restrict__ Whh,
                       const float* __restrict__ W2, const float* __restrict__ bm2,
                       uint4* __restrict__ gGA, uint2* __restrict__ gGB,
                       uint4* __restrict__ gUA, uint2* __restrict__ gUB,
                       float* __restrict__ gbb) {
    int t = blockIdx.x * blockDim.x + threadIdx.x;
    if (t < 2048) {
        int k4 = t >> 6, c = t & 63;
        float G[3][4];
#pragma unroll
        for (int g = 0; g < 3; g++)
#pragma unroll
            for (int kk = 0; kk < 4; kk++) {
                int j = 4 * k4 + kk;
                const float* w2r = W2 + (size_t)j * 64;
                const float* wir = Wih + (size_t)(g * 64 + c) * 64;
                float s = 0.f;
                for (int k = 0; k < 64; k++) s += w2r[k] * wir[k];
                G[g][kk] = s;
            }
        uint4 A; uint2 B;
        A.x = pkh(G[0][0], G[0][1]); A.y = pkh(G[1][0], G[1][1]);
        A.z = pkh(G[2][0], G[2][1]); A.w = pkh(G[0][2], G[0][3]);
        B.x = pkh(G[1][2], G[1][3]); B.y = pkh(G[2][2], G[2][3]);
        gGA[t] = A; gGB[t] = B;
    } else if (t < 3072) {
        int u = t - 2048;
        int k4 = u >> 6, c = u & 63;
        float U[3][4];
#pragma unroll
        for (int g = 0; g < 3; g++)
#pragma unroll
            for (int kk = 0; kk < 4; kk++)
                U[g][kk] = Whh[(size_t)(g * 64 + c) * 64 + 4 * k4 + kk];
        uint4 A; uint2 B;
        A.x = pkh(U[0][0], U[0][1]); A.y = pkh(U[1][0], U[1][1]);
        A.z = pkh(U[2][0], U[2][1]); A.w = pkh(U[0][2], U[0][3]);
        B.x = pkh(U[1][2], U[1][3]); B.y = pkh(U[2][2], U[2][3]);
        gUA[u] = A; gUB[u] = B;
    } else if (t < 3072 + 192) {
        int cg = t - 3072;
        const float* wir = Wih + (size_t)cg * 64;
        float s = 0.f;
        for (int k = 0; k < 64; k++) s += bm2[k] * wir[k];
        gbb[cg] = s;
    }
}

// ---------------- LSTM weight transpose ----------------
__global__ void k_packl(const float* __restrict__ lWih, const float* __restrict__ lWhh,
                        float* __restrict__ WT1, float* __restrict__ WT2) {
    int t = blockIdx.x * blockDim.x + threadIdx.x;
    if (t < 256 * 128) { int g = t >> 7, k = t & 127; WT1[k * 256 + g] = lWih[g * 128 + k]; }
    if (t < 256 * 64)  { int g = t >> 6, k = t & 63;  WT2[k * 256 + g] = lWhh[g * 64 + k]; }
}

// ---------------- node embedding ----------------
__global__ void k_embed(const float* __restrict__ xf, const float* __restrict__ We,
                        const float* __restrict__ be, float* __restrict__ xh, int N) {
    __shared__ float Wl[NDIM * HID];
    for (int t = threadIdx.x; t < NDIM * HID; t += blockDim.x) Wl[t] = We[t];
    __syncthreads();
    int total = N * HID;
    int stride = gridDim.x * blockDim.x;
    for (int idx = blockIdx.x * blockDim.x + threadIdx.x; idx < total; idx += stride) {
        int n = idx >> 6, c = idx & 63;
        const float* xr = xf + n * NDIM;
        float acc = be[c];
#pragma unroll
        for (int k = 0; k < NDIM; k++) acc += xr[k] * Wl[k * HID + c];
        xh[idx] = acc;
    }
}

// ---------------- k_prep: Pd (-> Hb, f32) and Ps (f16) ----------------
__global__ void __launch_bounds__(256)
k_prep(const float* __restrict__ xh, const float* __restrict__ Wm1,
       const float* __restrict__ bm1, float* __restrict__ Hb,
       _Float16* __restrict__ PsH, int N) {
    __shared__ float Wl[64 * 256];
    for (int t = threadIdx.x; t < 64 * 256; t += 256) {
        int k = t >> 8, cc = t & 255;
        Wl[t] = (cc < 128) ? Wm1[k * 128 + cc] : Wm1[(64 + k) * 128 + (cc - 128)];
    }
    __syncthreads();
    int wv = threadIdx.x >> 6, lane = threadIdx.x & 63;
    int cc = lane * 4;
    float4 bias;
    if (lane < 32) bias = *(const float4*)&bm1[cc];
    else bias = make_float4(0.f, 0.f, 0.f, 0.f);
    int ngroups = (N + 7) >> 3;
    for (int g = blockIdx.x * 4 + wv; g < ngroups; g += gridDim.x * 4) {
        int base = rfl(g) * 8;
        const float* xp[8];
#pragma unroll
        for (int t = 0; t < 8; t++) {
            int d = base + t; if (d > N - 1) d = N - 1;
            xp[t] = xh + (size_t)d * 64;
        }
        float4 acc[8];
#pragma unroll
        for (int t = 0; t < 8; t++) acc[t] = bias;
#pragma unroll 2
        for (int k4 = 0; k4 < 16; k4++) {
            int k = k4 * 4;
            float4 xv4[8];
#pragma unroll
            for (int t = 0; t < 8; t++) xv4[t] = *(const float4*)&xp[t][k];
#pragma unroll
            for (int kk = 0; kk < 4; kk++) {
                float4 w = *(const float4*)&Wl[(k + kk) * 256 + cc];
#pragma unroll
                for (int t = 0; t < 8; t++) {
                    float xv = kk == 0 ? xv4[t].x : kk == 1 ? xv4[t].y : kk == 2 ? xv4[t].z : xv4[t].w;
                    acc[t].x += xv * w.x; acc[t].y += xv * w.y;
                    acc[t].z += xv * w.z; acc[t].w += xv * w.w;
                }
            }
        }
#pragma unroll
        for (int t = 0; t < 8; t++) {
            int d = base + t;
            if (d < N) {
                if (lane < 32) *(float4*)&Hb[(size_t)d * 128 + cc] = acc[t];
                else {
                    h4 o;
                    o[0] = (_Float16)acc[t].x; o[1] = (_Float16)acc[t].y;
                    o[2] = (_Float16)acc[t].z; o[3] = (_Float16)acc[t].w;
                    *(h4*)&PsH[(size_t)d * 128 + (cc - 128)] = o;
                }
            }
        }
    }
}

// ---------------- k_edge: fdot2 inner product ----------------
__global__ void __launch_bounds__(256)
k_edge(const _Float16* __restrict__ PsH, const _Float16* __restrict__ eap,
       const float* __restrict__ Wm1, const int* __restrict__ ptr,
       const int* __restrict__ slist, float* __restrict__ Hb, int N) {
    int c = threadIdx.x & 127;
    int half = threadIdx.x >> 7;
    h2 wh[8];
#pragma unroll
    for (int k = 0; k < 8; k++) {
        h2 t;
        t[0] = (_Float16)Wm1[128 * 128 + (2 * k) * 128 + c];
        t[1] = (_Float16)Wm1[128 * 128 + (2 * k + 1) * 128 + c];
        wh[k] = t;
    }
    for (int dd = blockIdx.x * 2 + half; dd < N; dd += gridDim.x * 2) {
        int d = rfl(dd);
        float pd = Hb[(size_t)d * 128 + c];
        int eb = rfl(ptr[d]), ee = rfl(ptr[d + 1]);
        const int* sp = slist + eb;
        const _Float16* ep = eap + (size_t)eb * EDIM;
        int ne = ee - eb;
        float acc = 0.f;
        int i = 0;
        for (; i + 8 <= ne; i += 8) {
            int ns[8];
#pragma unroll
            for (int j = 0; j < 8; j++) ns[j] = rfl(sp[i + j]);
            float pv[8];
#pragma unroll
            for (int j = 0; j < 8; j++) pv[j] = (float)PsH[(size_t)ns[j] * 128 + c];
#pragma unroll
            for (int j = 0; j < 8; j++) {
                union { uint4 u; h2 h[4]; } A, B;
                A.u = *(const uint4*)(ep + (size_t)(i + j) * EDIM);
                B.u = *(const uint4*)(ep + (size_t)(i + j) * EDIM + 8);
                float pe = 0.f;
#pragma unroll
                for (int k = 0; k < 4; k++) pe = __builtin_amdgcn_fdot2(A.h[k], wh[k], pe, false);
#pragma unroll
                for (int k = 0; k < 4; k++) pe = __builtin_amdgcn_fdot2(B.h[k], wh[4 + k], pe, false);
                acc += fmaxf(pd + pv[j] + pe, 0.f);
            }
        }
        for (; i < ne; i++) {
            int n0 = rfl(sp[i]);
            float pv = (float)PsH[(size_t)n0 * 128 + c];
            union { uint4 u; h2 h[4]; } A, B;
            A.u = *(const uint4*)(ep + (size_t)i * EDIM);
            B.u = *(const uint4*)(ep + (size_t)i * EDIM + 8);
            float pe = 0.f;
#pragma unroll
            for (int k = 0; k < 4; k++) pe = __builtin_amdgcn_fdot2(A.h[k], wh[k], pe, false);
#pragma unroll
            for (int k = 0; k < 4; k++) pe = __builtin_amdgcn_fdot2(B.h[k], wh[4 + k], pe, false);
            acc += fmaxf(pd + pv + pe, 0.f);
        }
        Hb[(size_t)d * 128 + c] = acc;
    }
}

// ---------------- k_node: fused GRU, T=4 nodes per wave (amortized LDS reads, 4x ILP) ----------------
__global__ void __launch_bounds__(256)
k_node(const float* __restrict__ H, const uint4* __restrict__ gGA, const uint2* __restrict__ gGB,
       const uint4* __restrict__ gUA, const uint2* __restrict__ gUB,
       const float* __restrict__ gbb, const float* __restrict__ bih, const float* __restrict__ bhh,
       const int* __restrict__ ptr, const float* __restrict__ xin, float* __restrict__ xout, int N) {
    extern __shared__ char smem[];
    uint4* GA = (uint4*)smem;              // 32 KB
    uint2* GB = (uint2*)(smem + 32768);    // 16 KB
    uint4* UA = (uint4*)(smem + 49152);    // 16 KB
    uint2* UB = (uint2*)(smem + 65536);    //  8 KB
    for (int t = threadIdx.x; t < 2048; t += 256) { GA[t] = gGA[t]; GB[t] = gGB[t]; }
    for (int t = threadIdx.x; t < 1024; t += 256) { UA[t] = gUA[t]; UB[t] = gUB[t]; }
    __syncthreads();
    int wv = threadIdx.x >> 6, lane = threadIdx.x & 63;
    float gbr = gbb[lane], gbz = gbb[64 + lane], gbn = gbb[128 + lane];
    float br = bih[lane], bz = bih[64 + lane], bn = bih[128 + lane];
    float cr = bhh[lane], cz = bhh[64 + lane], cn = bhh[128 + lane];
    int ngroups = (N + 3) >> 2;
    for (int g = blockIdx.x * 4 + wv; g < ngroups; g += gridDim.x * 4) {
        int base = rfl(g) * 4;
        const float* hp[4]; const float* xp[4]; float deg[4];
#pragma unroll
        for (int t = 0; t < 4; t++) {
            int d = base + t; if (d > N - 1) d = N - 1;
            hp[t] = H + (size_t)d * 128;
            xp[t] = xin + (size_t)d * 64;
            deg[t] = (float)(ptr[d + 1] - ptr[d]);
        }
        float gr[4], gz[4], gn[4];
#pragma unroll
        for (int t = 0; t < 4; t++) {
            gr[t] = br + deg[t] * gbr;
            gz[t] = bz + deg[t] * gbz;
            gn[t] = bn + deg[t] * gbn;
        }
#pragma unroll 2
        for (int k4 = 0; k4 < 32; k4++) {
            uint4 wa = GA[k4 * 64 + lane];
            uint2 wb = GB[k4 * 64 + lane];
#pragma unroll
            for (int t = 0; t < 4; t++) {
                float4 hx = *(const float4*)&hp[t][k4 * 4];
                h2 a01 = pk2h(hx.x, hx.y), a23 = pk2h(hx.z, hx.w);
                gr[t] = fdot2_(a01, wa.x, gr[t]); gz[t] = fdot2_(a01, wa.y, gz[t]);
                gn[t] = fdot2_(a01, wa.z, gn[t]);
                gr[t] = fdot2_(a23, wa.w, gr[t]); gz[t] = fdot2_(a23, wb.x, gz[t]);
                gn[t] = fdot2_(a23, wb.y, gn[t]);
            }
        }
        float hr[4], hz[4], hn[4], hv[4];
#pragma unroll
        for (int t = 0; t < 4; t++) { hr[t] = cr; hz[t] = cz; hn[t] = cn; hv[t] = xp[t][lane]; }
#pragma unroll 2
        for (int k4 = 0; k4 < 16; k4++) {
            uint4 wa = UA[k4 * 64 + lane];
            uint2 wb = UB[k4 * 64 + lane];
#pragma unroll
            for (int t = 0; t < 4; t++) {
                float4 hx = *(const float4*)&xp[t][k4 * 4];
                h2 a01 = pk2h(hx.x, hx.y), a23 = pk2h(hx.z, hx.w);
                hr[t] = fdot2_(a01, wa.x, hr[t]); hz[t] = fdot2_(a01, wa.y, hz[t]);
                hn[t] = fdot2_(a01, wa.z, hn[t]);
                hr[t] = fdot2_(a23, wa.w, hr[t]); hz[t] = fdot2_(a23, wb.x, hz[t]);
                hn[t] = fdot2_(a23, wb.y, hn[t]);
            }
        }
#pragma unroll
        for (int t = 0; t < 4; t++) {
            int d = base + t;
            if (d < N) {
                float r = sigm(gr[t] + hr[t]);
                float z = sigm(gz[t] + hz[t]);
                float nn = tanhf(gn[t] + r * hn[t]);
                xout[(size_t)d * 64 + lane] = (1.f - z) * nn + z * hv[t];
            }
        }
    }
}

// ---------------- fused Set2Set ----------------
__global__ void __launch_bounds__(1024)
k_s2s(const float* __restrict__ xh, const int* __restrict__ gptr,
      const float* __restrict__ WT1, const float* __restrict__ WT2,
      const float* __restrict__ lbih, const float* __restrict__ lbhh,
      const float* __restrict__ Wr1, const float* __restrict__ br1,
      const float* __restrict__ Wr2, const float* __restrict__ br2,
      float* __restrict__ out) {
    int b = blockIdx.x, tid = threadIdx.x;
    __shared__ float xl[SCAP * 64];
    __shared__ float qs[128], qhl[64], qcs[64], g[256], red[16], asums[16], rvs[1024];
    int start = gptr[b], end = gptr[b + 1];
    int seg = end - start;
    bool uselds = (seg <= SCAP);
    if (uselds) {
        int tot = seg * 64;
        for (int t = tid; t < tot; t += 1024) xl[t] = xh[(size_t)start * 64 + t];
    }
    if (tid < 128) qs[tid] = 0.f;
    if (tid < 64) { qhl[tid] = 0.f; qcs[tid] = 0.f; }
    __syncthreads();
    int grp = tid >> 6, lane = tid & 63;
    int gate = tid & 255, part = tid >> 8;
    for (int s = 0; s < 6; s++) {
        {
            float acc = 0.f;
            int k0 = part * 32;
#pragma unroll 8
            for (int k = k0; k < k0 + 32; k++) acc += qs[k] * WT1[k * 256 + gate];
            int k1 = part * 16;
#pragma unroll 8
            for (int k = k1; k < k1 + 16; k++) acc += qhl[k] * WT2[k * 256 + gate];
            rvs[tid] = acc;
        }
        __syncthreads();
        if (tid < 256) g[tid] = lbih[tid] + lbhh[tid] + rvs[tid] + rvs[256 + tid] + rvs[512 + tid] + rvs[768 + tid];
        __syncthreads();
        if (tid < 64) {
            float ig = sigm(g[tid]), fg = sigm(g[64 + tid]);
            float gg = tanhf(g[128 + tid]), og = sigm(g[192 + tid]);
            float c = fg * qcs[tid] + ig * gg;
            float h = og * tanhf(c);
            qcs[tid] = c; qhl[tid] = h; qs[tid] = h;
        }
        __syncthreads();
        float qv = qhl[lane];
        float mloc = -3.4e38f, asl = 0.f, rv = 0.f;
        for (int n = grp; n < seg; n += 16) {
            float xv = uselds ? xl[n * 64 + lane] : xh[(size_t)(start + n) * 64 + lane];
            float p = xv * qv;
#pragma unroll
            for (int off = 32; off > 0; off >>= 1) p += __shfl_xor(p, off);
            float mnew = fmaxf(mloc, p);
            float corr = expf(mloc - mnew);
            float a = expf(p - mnew);
            asl = asl * corr + a;
            rv = rv * corr + a * xv;
            mloc = mnew;
        }
        if (lane == 0) red[grp] = mloc;
        __syncthreads();
        float gmax = red[0];
#pragma unroll
        for (int j = 1; j < 16; j++) gmax = fmaxf(gmax, red[j]);
        float sc = expf(mloc - gmax);
        rvs[tid] = rv * sc;
        if (lane == 0) asums[grp] = asl * sc;
        __syncthreads();
        if (tid < 64) {
            float rt = 0.f, at = 0.f;
#pragma unroll
            for (int j = 0; j < 16; j++) { rt += rvs[tid + 64 * j]; at += asums[j]; }
            qs[64 + tid] = (at > 0.f) ? rt / at : 0.f;
        }
        __syncthreads();
    }
    if (tid < 64) {
        float a2 = br1[tid];
#pragma unroll 8
        for (int k = 0; k < 128; k++) a2 += qs[k] * Wr1[k * 64 + tid];
        a2 = fmaxf(a2, 0.f);
        float v = a2 * Wr2[tid];
#pragma unroll
        for (int off = 32; off > 0; off >>= 1) v += __shfl_xor(v, off);
        if (tid == 0) out[b] = v + br2[0];
    }
}

extern "C" void kernel_launch(void* const* d_in, const int* in_sizes, int n_in,
                              void* d_out, int out_size, void* d_ws, size_t ws_size,
                              hipStream_t stream) {
    const float* x_feat = (const float*)d_in[0];
    const int*   ei     = (const int*)d_in[1];
    const float* eattr  = (const float*)d_in[2];
    const int*   batch  = (const int*)d_in[3];
    const float* W_emb  = (const float*)d_in[4];
    const float* b_emb  = (const float*)d_in[5];
    const float* W_m1   = (const float*)d_in[6];
    const float* b_m1   = (const float*)d_in[7];
    const float* W_m2   = (const float*)d_in[8];
    const float* b_m2   = (const float*)d_in[9];
    const float* gWih   = (const float*)d_in[10];
    const float* gWhh   = (const float*)d_in[11];
    const float* gbih   = (const float*)d_in[12];
    const float* gbhh   = (const float*)d_in[13];
    const float* lWih   = (const float*)d_in[14];
    const float* lWhh   = (const float*)d_in[15];
    const float* lbih   = (const float*)d_in[16];
    const float* lbhh   = (const float*)d_in[17];
    const float* Wr1    = (const float*)d_in[18];
    const float* br1    = (const float*)d_in[19];
    const float* Wr2    = (const float*)d_in[20];
    const float* br2    = (const float*)d_in[21];

    int N = in_sizes[0] / NDIM;   // 50000
    int E = in_sizes[1] / 2;      // 800000

    char* w = (char*)d_ws;
    auto alloc = [&](size_t b) { char* p = w; w += (b + 511) & ~(size_t)511; return p; };
    float*     xh    = (float*)alloc((size_t)N * 64 * 4);
    float*     xh2   = (float*)alloc((size_t)N * 64 * 4);
    _Float16*  PsH   = (_Float16*)alloc((size_t)N * 128 * 2);
    float*     Hb    = (float*)alloc((size_t)N * 128 * 4);
    int*       ptr   = (int*)alloc((size_t)(N + 1) * 4);
    int*       slist = (int*)alloc((size_t)E * 4);
    _Float16*  eap   = (_Float16*)alloc((size_t)E * EDIM * 2);
    uint4*     gGA   = (uint4*)alloc((size_t)2048 * 16);
    uint2*     gGB   = (uint2*)alloc((size_t)2048 * 8);
    uint4*     gUA   = (uint4*)alloc((size_t)1024 * 16);
    uint2*     gUB   = (uint2*)alloc((size_t)1024 * 8);
    float*     gbb   = (float*)alloc((size_t)192 * 4);
    float*     WT1   = (float*)alloc((size_t)128 * 256 * 4);
    float*     WT2   = (float*)alloc((size_t)64 * 256 * 4);
    int*       gptr  = (int*)alloc((size_t)(NG + 1) * 4);
    int*       bsum  = (int*)alloc(128 * 4);
    int*       boff  = (int*)alloc(128 * 4);
    char* z0 = w;
    int*       cnt    = (int*)alloc((size_t)N * 4);
    int*       cursor = (int*)alloc((size_t)N * 4);
    char* z0e = w;

    hipMemsetAsync(z0, 0, (size_t)(z0e - z0), stream);

    hipError_t attr_err = hipFuncSetAttribute((const void*)k_node,
        hipFuncAttributeMaxDynamicSharedMemorySize, 73728);
    (void)attr_err;

    int NB = (N + 1023) / 1024;
    k_hist<<<1024, 256, 0, stream>>>(ei + E, E, cnt);
    k_scanA<<<NB, 1024, 0, stream>>>(cnt, ptr, bsum, N);
    k_scanB<<<1, 64, 0, stream>>>(bsum, boff, NB);
    k_scanC<<<(N + 256) / 256, 256, 0, stream>>>(ptr, boff, N, NB);
    k_gptr<<<3, 256, 0, stream>>>(batch, N, gptr);
    k_scatter<<<3125, 256, 0, stream>>>(ei, ei + E, eattr, E, ptr, cursor, slist, eap);
    k_fuse<<<13, 256, 0, stream>>>(gWih, gWhh, W_m2, b_m2, gGA, gGB, gUA, gUB, gbb);
    k_packl<<<128, 256, 0, stream>>>(lWih, lWhh, WT1, WT2);

    k_embed<<<2048, 256, 0, stream>>>(x_feat, W_emb, b_emb, xh, N);

    float* xa = xh;
    float* xb = xh2;
    for (int r = 0; r < 3; r++) {
        k_prep<<<391, 256, 0, stream>>>(xa, W_m1, b_m1, Hb, PsH, N);
        k_edge<<<4096, 256, 0, stream>>>(PsH, eap, W_m1, ptr, slist, Hb, N);
        k_node<<<512, 256, 73728, stream>>>(Hb, gGA, gGB, gUA, gUB, gbb, gbih, gbhh,
                                            ptr, xa, xb, N);
        float* t = xa; xa = xb; xb = t;
    }
    k_s2s<<<NG, 1024, 0, stream>>>(xa, gptr, WT1, WT2, lbih, lbhh,
                                   Wr1, br1, Wr2, br2, (float*)d_out);
}

// Round 12
// 926.395 us; speedup vs baseline: 1.1562x; 1.0231x over previous
//
#include <hip/hip_runtime.h>
#include <hip/hip_bf16.h>

#define HID 64
#define MSG 128
#define NDIM 32
#define EDIM 16
#define NG 512
#define SCAP 192

typedef unsigned short u16;
typedef unsigned int u32;
typedef _Float16 h8 __attribute__((ext_vector_type(8)));
typedef _Float16 h4 __attribute__((ext_vector_type(4)));
typedef _Float16 h2 __attribute__((ext_vector_type(2)));

__device__ __forceinline__ float sigm(float x){return 1.0f/(1.0f+expf(-x));}
__device__ __forceinline__ int rfl(int x){return __builtin_amdgcn_readfirstlane(x);}
__device__ __forceinline__ u32 pkh(float a, float b){
    union { h2 h; u32 u; } v; v.h[0] = (_Float16)a; v.h[1] = (_Float16)b; return v.u;
}
__device__ __forceinline__ h2 pk2h(float a, float b){
    union { __fp16 __attribute__((ext_vector_type(2))) r; h2 h; } v;
    v.r = __builtin_amdgcn_cvt_pkrtz(a, b);
    return v.h;
}
__device__ __forceinline__ float fdot2_(h2 a, u32 w, float c){
    union { u32 u; h2 h; } v; v.u = w;
    return __builtin_amdgcn_fdot2(a, v.h, c, false);
}

// ---------------- CSR build ----------------
__global__ void k_hist(const int* __restrict__ idx, int n, int* __restrict__ cnt) {
    int i = blockIdx.x * blockDim.x + threadIdx.x;
    int stride = gridDim.x * blockDim.x;
    for (; i < n; i += stride) atomicAdd(&cnt[idx[i]], 1);
}

__global__ void k_scanA(const int* __restrict__ in, int* __restrict__ out,
                        int* __restrict__ bsum, int n) {
    __shared__ int sh[1024];
    int i = blockIdx.x * 1024 + threadIdx.x;
    int v = (i < n) ? in[i] : 0;
    sh[threadIdx.x] = v;
    __syncthreads();
    for (int off = 1; off < 1024; off <<= 1) {
        int t = (threadIdx.x >= off) ? sh[threadIdx.x - off] : 0;
        __syncthreads();
        sh[threadIdx.x] += t;
        __syncthreads();
    }
    if (i < n) out[i] = sh[threadIdx.x] - v;
    if (threadIdx.x == 1023) bsum[blockIdx.x] = sh[1023];
}
__global__ void k_scanB(const int* __restrict__ bsum, int* __restrict__ boff, int nb) {
    if (threadIdx.x == 0) {
        int r = 0;
        for (int b = 0; b < nb; b++) { boff[b] = r; r += bsum[b]; }
        boff[nb] = r;
    }
}
__global__ void k_scanC(int* __restrict__ out, const int* __restrict__ boff, int n, int nb) {
    int i = blockIdx.x * blockDim.x + threadIdx.x;
    if (i < n) out[i] += boff[i >> 10];
    else if (i == n) out[n] = boff[nb];
}

__global__ void k_gptr(const int* __restrict__ batch, int N, int* __restrict__ gptr) {
    int g = blockIdx.x * blockDim.x + threadIdx.x;
    if (g > NG) return;
    int lo = 0, hi = N;
    while (lo < hi) { int mid = (lo + hi) >> 1; if (batch[mid] < g) lo = mid + 1; else hi = mid; }
    gptr[g] = lo;
}

// scatter + edge_attr permute (fp16) fused
__global__ void k_scatter(const int* __restrict__ src, const int* __restrict__ dst,
                          const float* __restrict__ ea, int n,
                          const int* __restrict__ ptr, int* __restrict__ cursor,
                          int* __restrict__ slist, _Float16* __restrict__ eap) {
    int i = blockIdx.x * blockDim.x + threadIdx.x;
    int stride = gridDim.x * blockDim.x;
    for (; i < n; i += stride) {
        int d = dst[i];
        int pos = ptr[d] + atomicAdd(&cursor[d], 1);
        slist[pos] = src[i];
        const float* s = ea + (size_t)i * EDIM;
        float4 a = *(const float4*)s, b = *(const float4*)(s + 4);
        float4 c = *(const float4*)(s + 8), d4 = *(const float4*)(s + 12);
        h8 o0, o1;
        o0[0]=(_Float16)a.x; o0[1]=(_Float16)a.y; o0[2]=(_Float16)a.z; o0[3]=(_Float16)a.w;
        o0[4]=(_Float16)b.x; o0[5]=(_Float16)b.y; o0[6]=(_Float16)b.z; o0[7]=(_Float16)b.w;
        o1[0]=(_Float16)c.x; o1[1]=(_Float16)c.y; o1[2]=(_Float16)c.z; o1[3]=(_Float16)c.w;
        o1[4]=(_Float16)d4.x; o1[5]=(_Float16)d4.y; o1[6]=(_Float16)d4.z; o1[7]=(_Float16)d4.w;
        h8* dp = (h8*)(eap + (size_t)pos * EDIM);
        dp[0] = o0; dp[1] = o1;
    }
}

// ---------------- fuse W2 into GRU input gates ----------------
__global__ void k_fuse(const float* __restrict__ Wih, const float* __restrict__ Whh,
                       const float* __restrict__ W2, const float* __restrict__ bm2,
                       uint4* __restrict__ gGA, uint2* __restrict__ gGB,
                       uint4* __restrict__ gUA, uint2* __restrict__ gUB,
                       float* __restrict__ gbb) {
    int t = blockIdx.x * blockDim.x + threadIdx.x;
    if (t < 2048) {
        int k4 = t >> 6, c = t & 63;
        float G[3][4];
#pragma unroll
        for (int g = 0; g < 3; g++)
#pragma unroll
            for (int kk = 0; kk < 4; kk++) {
                int j = 4 * k4 + kk;
                const float* w2r = W2 + (size_t)j * 64;
                const float* wir = Wih + (size_t)(g * 64 + c) * 64;
                float s = 0.f;
                for (int k = 0; k < 64; k++) s += w2r[k] * wir[k];
                G[g][kk] = s;
            }
        uint4 A; uint2 B;
        A.x = pkh(G[0][0], G[0][1]); A.y = pkh(G[1][0], G[1][1]);
        A.z = pkh(G[2][0], G[2][1]); A.w = pkh(G[0][2], G[0][3]);
        B.x = pkh(G[1][2], G[1][3]); B.y = pkh(G[2][2], G[2][3]);
        gGA[t] = A; gGB[t] = B;
    } else if (t < 3072) {
        int u = t - 2048;
        int k4 = u >> 6, c = u & 63;
        float U[3][4];
#pragma unroll
        for (int g = 0; g < 3; g++)
#pragma unroll
            for (int kk = 0; kk < 4; kk++)
                U[g][kk] = Whh[(size_t)(g * 64 + c) * 64 + 4 * k4 + kk];
        uint4 A; uint2 B;
        A.x = pkh(U[0][0], U[0][1]); A.y = pkh(U[1][0], U[1][1]);
        A.z = pkh(U[2][0], U[2][1]); A.w = pkh(U[0][2], U[0][3]);
        B.x = pkh(U[1][2], U[1][3]); B.y = pkh(U[2][2], U[2][3]);
        gUA[u] = A; gUB[u] = B;
    } else if (t < 3072 + 192) {
        int cg = t - 3072;
        const float* wir = Wih + (size_t)cg * 64;
        float s = 0.f;
        for (int k = 0; k < 64; k++) s += bm2[k] * wir[k];
        gbb[cg] = s;
    }
}

// ---------------- LSTM weight transpose ----------------
__global__ void k_packl(const float* __restrict__ lWih, const float* __restrict__ lWhh,
                        float* __restrict__ WT1, float* __restrict__ WT2) {
    int t = blockIdx.x * blockDim.x + threadIdx.x;
    if (t < 256 * 128) { int g = t >> 7, k = t & 127; WT1[k * 256 + g] = lWih[g * 128 + k]; }
    if (t < 256 * 64)  { int g = t >> 6, k = t & 63;  WT2[k * 256 + g] = lWhh[g * 64 + k]; }
}

// ---------------- node embedding ----------------
__global__ void k_embed(const float* __restrict__ xf, const float* __restrict__ We,
                        const float* __restrict__ be, float* __restrict__ xh, int N) {
    __shared__ float Wl[NDIM * HID];
    for (int t = threadIdx.x; t < NDIM * HID; t += blockDim.x) Wl[t] = We[t];
    __syncthreads();
    int total = N * HID;
    int stride = gridDim.x * blockDim.x;
    for (int idx = blockIdx.x * blockDim.x + threadIdx.x; idx < total; idx += stride) {
        int n = idx >> 6, c = idx & 63;
        const float* xr = xf + n * NDIM;
        float acc = be[c];
#pragma unroll
        for (int k = 0; k < NDIM; k++) acc += xr[k] * Wl[k * HID + c];
        xh[idx] = acc;
    }
}

// ---------------- k_prep: Pd (-> Hb, f32) and Ps (f16); block = 512 (8 waves) ----------------
__global__ void __launch_bounds__(512)
k_prep(const float* __restrict__ xh, const float* __restrict__ Wm1,
       const float* __restrict__ bm1, float* __restrict__ Hb,
       _Float16* __restrict__ PsH, int N) {
    __shared__ float Wl[64 * 256];
    for (int t = threadIdx.x; t < 64 * 256; t += 512) {
        int k = t >> 8, cc = t & 255;
        Wl[t] = (cc < 128) ? Wm1[k * 128 + cc] : Wm1[(64 + k) * 128 + (cc - 128)];
    }
    __syncthreads();
    int wv = threadIdx.x >> 6, lane = threadIdx.x & 63;
    int cc = lane * 4;
    float4 bias;
    if (lane < 32) bias = *(const float4*)&bm1[cc];
    else bias = make_float4(0.f, 0.f, 0.f, 0.f);
    int ngroups = (N + 7) >> 3;
    for (int g = blockIdx.x * 8 + wv; g < ngroups; g += gridDim.x * 8) {
        int base = rfl(g) * 8;
        const float* xp[8];
#pragma unroll
        for (int t = 0; t < 8; t++) {
            int d = base + t; if (d > N - 1) d = N - 1;
            xp[t] = xh + (size_t)d * 64;
        }
        float4 acc[8];
#pragma unroll
        for (int t = 0; t < 8; t++) acc[t] = bias;
#pragma unroll 2
        for (int k4 = 0; k4 < 16; k4++) {
            int k = k4 * 4;
            float4 xv4[8];
#pragma unroll
            for (int t = 0; t < 8; t++) xv4[t] = *(const float4*)&xp[t][k];
#pragma unroll
            for (int kk = 0; kk < 4; kk++) {
                float4 w = *(const float4*)&Wl[(k + kk) * 256 + cc];
#pragma unroll
                for (int t = 0; t < 8; t++) {
                    float xv = kk == 0 ? xv4[t].x : kk == 1 ? xv4[t].y : kk == 2 ? xv4[t].z : xv4[t].w;
                    acc[t].x += xv * w.x; acc[t].y += xv * w.y;
                    acc[t].z += xv * w.z; acc[t].w += xv * w.w;
                }
            }
        }
#pragma unroll
        for (int t = 0; t < 8; t++) {
            int d = base + t;
            if (d < N) {
                if (lane < 32) *(float4*)&Hb[(size_t)d * 128 + cc] = acc[t];
                else {
                    h4 o;
                    o[0] = (_Float16)acc[t].x; o[1] = (_Float16)acc[t].y;
                    o[2] = (_Float16)acc[t].z; o[3] = (_Float16)acc[t].w;
                    *(h4*)&PsH[(size_t)d * 128 + (cc - 128)] = o;
                }
            }
        }
    }
}

// ---------------- k_edge: fdot2 inner product ----------------
__global__ void __launch_bounds__(256)
k_edge(const _Float16* __restrict__ PsH, const _Float16* __restrict__ eap,
       const float* __restrict__ Wm1, const int* __restrict__ ptr,
       const int* __restrict__ slist, float* __restrict__ Hb, int N) {
    int c = threadIdx.x & 127;
    int half = threadIdx.x >> 7;
    h2 wh[8];
#pragma unroll
    for (int k = 0; k < 8; k++) {
        h2 t;
        t[0] = (_Float16)Wm1[128 * 128 + (2 * k) * 128 + c];
        t[1] = (_Float16)Wm1[128 * 128 + (2 * k + 1) * 128 + c];
        wh[k] = t;
    }
    for (int dd = blockIdx.x * 2 + half; dd < N; dd += gridDim.x * 2) {
        int d = rfl(dd);
        float pd = Hb[(size_t)d * 128 + c];
        int eb = rfl(ptr[d]), ee = rfl(ptr[d + 1]);
        const int* sp = slist + eb;
        const _Float16* ep = eap + (size_t)eb * EDIM;
        int ne = ee - eb;
        float acc = 0.f;
        int i = 0;
        for (; i + 8 <= ne; i += 8) {
            int ns[8];
#pragma unroll
            for (int j = 0; j < 8; j++) ns[j] = rfl(sp[i + j]);
            float pv[8];
#pragma unroll
            for (int j = 0; j < 8; j++) pv[j] = (float)PsH[(size_t)ns[j] * 128 + c];
#pragma unroll
            for (int j = 0; j < 8; j++) {
                union { uint4 u; h2 h[4]; } A, B;
                A.u = *(const uint4*)(ep + (size_t)(i + j) * EDIM);
                B.u = *(const uint4*)(ep + (size_t)(i + j) * EDIM + 8);
                float pe = 0.f;
#pragma unroll
                for (int k = 0; k < 4; k++) pe = __builtin_amdgcn_fdot2(A.h[k], wh[k], pe, false);
#pragma unroll
                for (int k = 0; k < 4; k++) pe = __builtin_amdgcn_fdot2(B.h[k], wh[4 + k], pe, false);
                acc += fmaxf(pd + pv[j] + pe, 0.f);
            }
        }
        for (; i < ne; i++) {
            int n0 = rfl(sp[i]);
            float pv = (float)PsH[(size_t)n0 * 128 + c];
            union { uint4 u; h2 h[4]; } A, B;
            A.u = *(const uint4*)(ep + (size_t)i * EDIM);
            B.u = *(const uint4*)(ep + (size_t)i * EDIM + 8);
            float pe = 0.f;
#pragma unroll
            for (int k = 0; k < 4; k++) pe = __builtin_amdgcn_fdot2(A.h[k], wh[k], pe, false);
#pragma unroll
            for (int k = 0; k < 4; k++) pe = __builtin_amdgcn_fdot2(B.h[k], wh[4 + k], pe, false);
            acc += fmaxf(pd + pv + pe, 0.f);
        }
        Hb[(size_t)d * 128 + c] = acc;
    }
}

// ---------------- k_node: fused GRU, T=4, block = 1024 (16 waves share the 72KB LDS) ----------------
__global__ void __launch_bounds__(1024)
k_node(const float* __restrict__ H, const uint4* __restrict__ gGA, const uint2* __restrict__ gGB,
       const uint4* __restrict__ gUA, const uint2* __restrict__ gUB,
       const float* __restrict__ gbb, const float* __restrict__ bih, const float* __restrict__ bhh,
       const int* __restrict__ ptr, const float* __restrict__ xin, float* __restrict__ xout, int N) {
    extern __shared__ char smem[];
    uint4* GA = (uint4*)smem;              // 32 KB
    uint2* GB = (uint2*)(smem + 32768);    // 16 KB
    uint4* UA = (uint4*)(smem + 49152);    // 16 KB
    uint2* UB = (uint2*)(smem + 65536);    //  8 KB
    for (int t = threadIdx.x; t < 2048; t += 1024) { GA[t] = gGA[t]; GB[t] = gGB[t]; }
    for (int t = threadIdx.x; t < 1024; t += 1024) { UA[t] = gUA[t]; UB[t] = gUB[t]; }
    __syncthreads();
    int wv = threadIdx.x >> 6, lane = threadIdx.x & 63;
    float gbr = gbb[lane], gbz = gbb[64 + lane], gbn = gbb[128 + lane];
    float br = bih[lane], bz = bih[64 + lane], bn = bih[128 + lane];
    float cr = bhh[lane], cz = bhh[64 + lane], cn = bhh[128 + lane];
    int ngroups = (N + 3) >> 2;
    for (int g = blockIdx.x * 16 + wv; g < ngroups; g += gridDim.x * 16) {
        int base = rfl(g) * 4;
        const float* hp[4]; const float* xp[4]; float deg[4];
#pragma unroll
        for (int t = 0; t < 4; t++) {
            int d = base + t; if (d > N - 1) d = N - 1;
            hp[t] = H + (size_t)d * 128;
            xp[t] = xin + (size_t)d * 64;
            deg[t] = (float)(ptr[d + 1] - ptr[d]);
        }
        float gr[4], gz[4], gn[4];
#pragma unroll
        for (int t = 0; t < 4; t++) {
            gr[t] = br + deg[t] * gbr;
            gz[t] = bz + deg[t] * gbz;
            gn[t] = bn + deg[t] * gbn;
        }
#pragma unroll 2
        for (int k4 = 0; k4 < 32; k4++) {
            uint4 wa = GA[k4 * 64 + lane];
            uint2 wb = GB[k4 * 64 + lane];
#pragma unroll
            for (int t = 0; t < 4; t++) {
                float4 hx = *(const float4*)&hp[t][k4 * 4];
                h2 a01 = pk2h(hx.x, hx.y), a23 = pk2h(hx.z, hx.w);
                gr[t] = fdot2_(a01, wa.x, gr[t]); gz[t] = fdot2_(a01, wa.y, gz[t]);
                gn[t] = fdot2_(a01, wa.z, gn[t]);
                gr[t] = fdot2_(a23, wa.w, gr[t]); gz[t] = fdot2_(a23, wb.x, gz[t]);
                gn[t] = fdot2_(a23, wb.y, gn[t]);
            }
        }
        float hr[4], hz[4], hn[4], hv[4];
#pragma unroll
        for (int t = 0; t < 4; t++) { hr[t] = cr; hz[t] = cz; hn[t] = cn; hv[t] = xp[t][lane]; }
#pragma unroll 2
        for (int k4 = 0; k4 < 16; k4++) {
            uint4 wa = UA[k4 * 64 + lane];
            uint2 wb = UB[k4 * 64 + lane];
#pragma unroll
            for (int t = 0; t < 4; t++) {
                float4 hx = *(const float4*)&xp[t][k4 * 4];
                h2 a01 = pk2h(hx.x, hx.y), a23 = pk2h(hx.z, hx.w);
                hr[t] = fdot2_(a01, wa.x, hr[t]); hz[t] = fdot2_(a01, wa.y, hz[t]);
                hn[t] = fdot2_(a01, wa.z, hn[t]);
                hr[t] = fdot2_(a23, wa.w, hr[t]); hz[t] = fdot2_(a23, wb.x, hz[t]);
                hn[t] = fdot2_(a23, wb.y, hn[t]);
            }
        }
#pragma unroll
        for (int t = 0; t < 4; t++) {
            int d = base + t;
            if (d < N) {
                float r = sigm(gr[t] + hr[t]);
                float z = sigm(gz[t] + hz[t]);
                float nn = tanhf(gn[t] + r * hn[t]);
                xout[(size_t)d * 64 + lane] = (1.f - z) * nn + z * hv[t];
            }
        }
    }
}

// ---------------- fused Set2Set ----------------
__global__ void __launch_bounds__(1024)
k_s2s(const float* __restrict__ xh, const int* __restrict__ gptr,
      const float* __restrict__ WT1, const float* __restrict__ WT2,
      const float* __restrict__ lbih, const float* __restrict__ lbhh,
      const float* __restrict__ Wr1, const float* __restrict__ br1,
      const float* __restrict__ Wr2, const float* __restrict__ br2,
      float* __restrict__ out) {
    int b = blockIdx.x, tid = threadIdx.x;
    __shared__ float xl[SCAP * 64];
    __shared__ float qs[128], qhl[64], qcs[64], g[256], red[16], asums[16], rvs[1024];
    int start = gptr[b], end = gptr[b + 1];
    int seg = end - start;
    bool uselds = (seg <= SCAP);
    if (uselds) {
        int tot = seg * 64;
        for (int t = tid; t < tot; t += 1024) xl[t] = xh[(size_t)start * 64 + t];
    }
    if (tid < 128) qs[tid] = 0.f;
    if (tid < 64) { qhl[tid] = 0.f; qcs[tid] = 0.f; }
    __syncthreads();
    int grp = tid >> 6, lane = tid & 63;
    int gate = tid & 255, part = tid >> 8;
    for (int s = 0; s < 6; s++) {
        {
            float acc = 0.f;
            int k0 = part * 32;
#pragma unroll 8
            for (int k = k0; k < k0 + 32; k++) acc += qs[k] * WT1[k * 256 + gate];
            int k1 = part * 16;
#pragma unroll 8
            for (int k = k1; k < k1 + 16; k++) acc += qhl[k] * WT2[k * 256 + gate];
            rvs[tid] = acc;
        }
        __syncthreads();
        if (tid < 256) g[tid] = lbih[tid] + lbhh[tid] + rvs[tid] + rvs[256 + tid] + rvs[512 + tid] + rvs[768 + tid];
        __syncthreads();
        if (tid < 64) {
            float ig = sigm(g[tid]), fg = sigm(g[64 + tid]);
            float gg = tanhf(g[128 + tid]), og = sigm(g[192 + tid]);
            float c = fg * qcs[tid] + ig * gg;
            float h = og * tanhf(c);
            qcs[tid] = c; qhl[tid] = h; qs[tid] = h;
        }
        __syncthreads();
        float qv = qhl[lane];
        float mloc = -3.4e38f, asl = 0.f, rv = 0.f;
        for (int n = grp; n < seg; n += 16) {
            float xv = uselds ? xl[n * 64 + lane] : xh[(size_t)(start + n) * 64 + lane];
            float p = xv * qv;
#pragma unroll
            for (int off = 32; off > 0; off >>= 1) p += __shfl_xor(p, off);
            float mnew = fmaxf(mloc, p);
            float corr = expf(mloc - mnew);
            float a = expf(p - mnew);
            asl = asl * corr + a;
            rv = rv * corr + a * xv;
            mloc = mnew;
        }
        if (lane == 0) red[grp] = mloc;
        __syncthreads();
        float gmax = red[0];
#pragma unroll
        for (int j = 1; j < 16; j++) gmax = fmaxf(gmax, red[j]);
        float sc = expf(mloc - gmax);
        rvs[tid] = rv * sc;
        if (lane == 0) asums[grp] = asl * sc;
        __syncthreads();
        if (tid < 64) {
            float rt = 0.f, at = 0.f;
#pragma unroll
            for (int j = 0; j < 16; j++) { rt += rvs[tid + 64 * j]; at += asums[j]; }
            qs[64 + tid] = (at > 0.f) ? rt / at : 0.f;
        }
        __syncthreads();
    }
    if (tid < 64) {
        float a2 = br1[tid];
#pragma unroll 8
        for (int k = 0; k < 128; k++) a2 += qs[k] * Wr1[k * 64 + tid];
        a2 = fmaxf(a2, 0.f);
        float v = a2 * Wr2[tid];
#pragma unroll
        for (int off = 32; off > 0; off >>= 1) v += __shfl_xor(v, off);
        if (tid == 0) out[b] = v + br2[0];
    }
}

extern "C" void kernel_launch(void* const* d_in, const int* in_sizes, int n_in,
                              void* d_out, int out_size, void* d_ws, size_t ws_size,
                              hipStream_t stream) {
    const float* x_feat = (const float*)d_in[0];
    const int*   ei     = (const int*)d_in[1];
    const float* eattr  = (const float*)d_in[2];
    const int*   batch  = (const int*)d_in[3];
    const float* W_emb  = (const float*)d_in[4];
    const float* b_emb  = (const float*)d_in[5];
    const float* W_m1   = (const float*)d_in[6];
    const float* b_m1   = (const float*)d_in[7];
    const float* W_m2   = (const float*)d_in[8];
    const float* b_m2   = (const float*)d_in[9];
    const float* gWih   = (const float*)d_in[10];
    const float* gWhh   = (const float*)d_in[11];
    const float* gbih   = (const float*)d_in[12];
    const float* gbhh   = (const float*)d_in[13];
    const float* lWih   = (const float*)d_in[14];
    const float* lWhh   = (const float*)d_in[15];
    const float* lbih   = (const float*)d_in[16];
    const float* lbhh   = (const float*)d_in[17];
    const float* Wr1    = (const float*)d_in[18];
    const float* br1    = (const float*)d_in[19];
    const float* Wr2    = (const float*)d_in[20];
    const float* br2    = (const float*)d_in[21];

    int N = in_sizes[0] / NDIM;   // 50000
    int E = in_sizes[1] / 2;      // 800000

    char* w = (char*)d_ws;
    auto alloc = [&](size_t b) { char* p = w; w += (b + 511) & ~(size_t)511; return p; };
    float*     xh    = (float*)alloc((size_t)N * 64 * 4);
    float*     xh2   = (float*)alloc((size_t)N * 64 * 4);
    _Float16*  PsH   = (_Float16*)alloc((size_t)N * 128 * 2);
    float*     Hb    = (float*)alloc((size_t)N * 128 * 4);
    int*       ptr   = (int*)alloc((size_t)(N + 1) * 4);
    int*       slist = (int*)alloc((size_t)E * 4);
    _Float16*  eap   = (_Float16*)alloc((size_t)E * EDIM * 2);
    uint4*     gGA   = (uint4*)alloc((size_t)2048 * 16);
    uint2*     gGB   = (uint2*)alloc((size_t)2048 * 8);
    uint4*     gUA   = (uint4*)alloc((size_t)1024 * 16);
    uint2*     gUB   = (uint2*)alloc((size_t)1024 * 8);
    float*     gbb   = (float*)alloc((size_t)192 * 4);
    float*     WT1   = (float*)alloc((size_t)128 * 256 * 4);
    float*     WT2   = (float*)alloc((size_t)64 * 256 * 4);
    int*       gptr  = (int*)alloc((size_t)(NG + 1) * 4);
    int*       bsum  = (int*)alloc(128 * 4);
    int*       boff  = (int*)alloc(128 * 4);
    char* z0 = w;
    int*       cnt    = (int*)alloc((size_t)N * 4);
    int*       cursor = (int*)alloc((size_t)N * 4);
    char* z0e = w;

    hipMemsetAsync(z0, 0, (size_t)(z0e - z0), stream);

    hipError_t attr_err = hipFuncSetAttribute((const void*)k_node,
        hipFuncAttributeMaxDynamicSharedMemorySize, 73728);
    (void)attr_err;

    int NB = (N + 1023) / 1024;
    k_hist<<<1024, 256, 0, stream>>>(ei + E, E, cnt);
    k_scanA<<<NB, 1024, 0, stream>>>(cnt, ptr, bsum, N);
    k_scanB<<<1, 64, 0, stream>>>(bsum, boff, NB);
    k_scanC<<<(N + 256) / 256, 256, 0, stream>>>(ptr, boff, N, NB);
    k_gptr<<<3, 256, 0, stream>>>(batch, N, gptr);
    k_scatter<<<3125, 256, 0, stream>>>(ei, ei + E, eattr, E, ptr, cursor, slist, eap);
    k_fuse<<<13, 256, 0, stream>>>(gWih, gWhh, W_m2, b_m2, gGA, gGB, gUA, gUB, gbb);
    k_packl<<<128, 256, 0, stream>>>(lWih, lWhh, WT1, WT2);

    k_embed<<<2048, 256, 0, stream>>>(x_feat, W_emb, b_emb, xh, N);

    float* xa = xh;
    float* xb = xh2;
    for (int r = 0; r < 3; r++) {
        k_prep<<<196, 512, 0, stream>>>(xa, W_m1, b_m1, Hb, PsH, N);
        k_edge<<<4096, 256, 0, stream>>>(PsH, eap, W_m1, ptr, slist, Hb, N);
        k_node<<<256, 1024, 73728, stream>>>(Hb, gGA, gGB, gUA, gUB, gbb, gbih, gbhh,
                                             ptr, xa, xb, N);
        float* t = xa; xa = xb; xb = t;
    }
    k_s2s<<<NG, 1024, 0, stream>>>(xa, gptr, WT1, WT2, lbih, lbhh,
                                   Wr1, br1, Wr2, br2, (float*)d_out);
}

// Round 13
// 857.250 us; speedup vs baseline: 1.2495x; 1.0807x over previous
//
#include <hip/hip_runtime.h>
#include <hip/hip_bf16.h>

#define HID 64
#define MSG 128
#define NDIM 32
#define EDIM 16
#define NG 512
#define SCAP 192

typedef unsigned short u16;
typedef unsigned int u32;
typedef _Float16 h8 __attribute__((ext_vector_type(8)));
typedef _Float16 h4 __attribute__((ext_vector_type(4)));
typedef _Float16 h2 __attribute__((ext_vector_type(2)));

__device__ __forceinline__ float sigm(float x){return 1.0f/(1.0f+expf(-x));}
__device__ __forceinline__ int rfl(int x){return __builtin_amdgcn_readfirstlane(x);}
__device__ __forceinline__ u32 pkh(float a, float b){
    union { h2 h; u32 u; } v; v.h[0] = (_Float16)a; v.h[1] = (_Float16)b; return v.u;
}
__device__ __forceinline__ h2 bh2(u32 u){ union{u32 v; h2 h;} x; x.v=u; return x.h; }
__device__ __forceinline__ float fdot2_(h2 a, u32 w, float c){
    union { u32 u; h2 h; } v; v.u = w;
    return __builtin_amdgcn_fdot2(a, v.h, c, false);
}

// ---------------- CSR build ----------------
__global__ void k_hist(const int* __restrict__ idx, int n, int* __restrict__ cnt) {
    int i = blockIdx.x * blockDim.x + threadIdx.x;
    int stride = gridDim.x * blockDim.x;
    for (; i < n; i += stride) atomicAdd(&cnt[idx[i]], 1);
}

__global__ void k_scanA(const int* __restrict__ in, int* __restrict__ out,
                        int* __restrict__ bsum, int n) {
    __shared__ int sh[1024];
    int i = blockIdx.x * 1024 + threadIdx.x;
    int v = (i < n) ? in[i] : 0;
    sh[threadIdx.x] = v;
    __syncthreads();
    for (int off = 1; off < 1024; off <<= 1) {
        int t = (threadIdx.x >= off) ? sh[threadIdx.x - off] : 0;
        __syncthreads();
        sh[threadIdx.x] += t;
        __syncthreads();
    }
    if (i < n) out[i] = sh[threadIdx.x] - v;
    if (threadIdx.x == 1023) bsum[blockIdx.x] = sh[1023];
}
__global__ void k_scanB(const int* __restrict__ bsum, int* __restrict__ boff, int nb) {
    if (threadIdx.x == 0) {
        int r = 0;
        for (int b = 0; b < nb; b++) { boff[b] = r; r += bsum[b]; }
        boff[nb] = r;
    }
}
__global__ void k_scanC(int* __restrict__ out, const int* __restrict__ boff, int n, int nb) {
    int i = blockIdx.x * blockDim.x + threadIdx.x;
    if (i < n) out[i] += boff[i >> 10];
    else if (i == n) out[n] = boff[nb];
}

__global__ void k_gptr(const int* __restrict__ batch, int N, int* __restrict__ gptr) {
    int g = blockIdx.x * blockDim.x + threadIdx.x;
    if (g > NG) return;
    int lo = 0, hi = N;
    while (lo < hi) { int mid = (lo + hi) >> 1; if (batch[mid] < g) lo = mid + 1; else hi = mid; }
    gptr[g] = lo;
}

// scatter + edge_attr permute (fp16) fused
__global__ void k_scatter(const int* __restrict__ src, const int* __restrict__ dst,
                          const float* __restrict__ ea, int n,
                          const int* __restrict__ ptr, int* __restrict__ cursor,
                          int* __restrict__ slist, _Float16* __restrict__ eap) {
    int i = blockIdx.x * blockDim.x + threadIdx.x;
    int stride = gridDim.x * blockDim.x;
    for (; i < n; i += stride) {
        int d = dst[i];
        int pos = ptr[d] + atomicAdd(&cursor[d], 1);
        slist[pos] = src[i];
        const float* s = ea + (size_t)i * EDIM;
        float4 a = *(const float4*)s, b = *(const float4*)(s + 4);
        float4 c = *(const float4*)(s + 8), d4 = *(const float4*)(s + 12);
        h8 o0, o1;
        o0[0]=(_Float16)a.x; o0[1]=(_Float16)a.y; o0[2]=(_Float16)a.z; o0[3]=(_Float16)a.w;
        o0[4]=(_Float16)b.x; o0[5]=(_Float16)b.y; o0[6]=(_Float16)b.z; o0[7]=(_Float16)b.w;
        o1[0]=(_Float16)c.x; o1[1]=(_Float16)c.y; o1[2]=(_Float16)c.z; o1[3]=(_Float16)c.w;
        o1[4]=(_Float16)d4.x; o1[5]=(_Float16)d4.y; o1[6]=(_Float16)d4.z; o1[7]=(_Float16)d4.w;
        h8* dp = (h8*)(eap + (size_t)pos * EDIM);
        dp[0] = o0; dp[1] = o1;
    }
}

// ---------------- fuse W2 into GRU input gates ----------------
__global__ void k_fuse(const float* __restrict__ Wih, const float* __restrict__ Whh,
                       const float* __restrict__ W2, const float* __restrict__ bm2,
                       uint4* __restrict__ gGA, uint2* __restrict__ gGB,
                       uint4* __restrict__ gUA, uint2* __restrict__ gUB,
                       float* __restrict__ gbb) {
    int t = blockIdx.x * blockDim.x + threadIdx.x;
    if (t < 2048) {
        int k4 = t >> 6, c = t & 63;
        float G[3][4];
#pragma unroll
        for (int g = 0; g < 3; g++)
#pragma unroll
            for (int kk = 0; kk < 4; kk++) {
                int j = 4 * k4 + kk;
                const float* w2r = W2 + (size_t)j * 64;
                const float* wir = Wih + (size_t)(g * 64 + c) * 64;
                float s = 0.f;
                for (int k = 0; k < 64; k++) s += w2r[k] * wir[k];
                G[g][kk] = s;
            }
        uint4 A; uint2 B;
        A.x = pkh(G[0][0], G[0][1]); A.y = pkh(G[1][0], G[1][1]);
        A.z = pkh(G[2][0], G[2][1]); A.w = pkh(G[0][2], G[0][3]);
        B.x = pkh(G[1][2], G[1][3]); B.y = pkh(G[2][2], G[2][3]);
        gGA[t] = A; gGB[t] = B;
    } else if (t < 3072) {
        int u = t - 2048;
        int k4 = u >> 6, c = u & 63;
        float U[3][4];
#pragma unroll
        for (int g = 0; g < 3; g++)
#pragma unroll
            for (int kk = 0; kk < 4; kk++)
                U[g][kk] = Whh[(size_t)(g * 64 + c) * 64 + 4 * k4 + kk];
        uint4 A; uint2 B;
        A.x = pkh(U[0][0], U[0][1]); A.y = pkh(U[1][0], U[1][1]);
        A.z = pkh(U[2][0], U[2][1]); A.w = pkh(U[0][2], U[0][3]);
        B.x = pkh(U[1][2], U[1][3]); B.y = pkh(U[2][2], U[2][3]);
        gUA[u] = A; gUB[u] = B;
    } else if (t < 3072 + 192) {
        int cg = t - 3072;
        const float* wir = Wih + (size_t)cg * 64;
        float s = 0.f;
        for (int k = 0; k < 64; k++) s += bm2[k] * wir[k];
        gbb[cg] = s;
    }
}

// ---------------- LSTM weight transpose ----------------
__global__ void k_packl(const float* __restrict__ lWih, const float* __restrict__ lWhh,
                        float* __restrict__ WT1, float* __restrict__ WT2) {
    int t = blockIdx.x * blockDim.x + threadIdx.x;
    if (t < 256 * 128) { int g = t >> 7, k = t & 127; WT1[k * 256 + g] = lWih[g * 128 + k]; }
    if (t < 256 * 64)  { int g = t >> 6, k = t & 63;  WT2[k * 256 + g] = lWhh[g * 64 + k]; }
}

// ---------------- node embedding: writes f32 and fp16 mirrors ----------------
__global__ void k_embed(const float* __restrict__ xf, const float* __restrict__ We,
                        const float* __restrict__ be, float* __restrict__ xh,
                        _Float16* __restrict__ xh16, int N) {
    __shared__ float Wl[NDIM * HID];
    for (int t = threadIdx.x; t < NDIM * HID; t += blockDim.x) Wl[t] = We[t];
    __syncthreads();
    int total = N * HID;
    int stride = gridDim.x * blockDim.x;
    for (int idx = blockIdx.x * blockDim.x + threadIdx.x; idx < total; idx += stride) {
        int n = idx >> 6, c = idx & 63;
        const float* xr = xf + n * NDIM;
        float acc = be[c];
#pragma unroll
        for (int k = 0; k < NDIM; k++) acc += xr[k] * Wl[k * HID + c];
        xh[idx] = acc;
        xh16[idx] = (_Float16)acc;
    }
}

// ---------------- k_prep: Pd (-> Hb, f32) and Ps (f16); block = 512 ----------------
__global__ void __launch_bounds__(512)
k_prep(const float* __restrict__ xh, const float* __restrict__ Wm1,
       const float* __restrict__ bm1, float* __restrict__ Hb,
       _Float16* __restrict__ PsH, int N) {
    __shared__ float Wl[64 * 256];
    for (int t = threadIdx.x; t < 64 * 256; t += 512) {
        int k = t >> 8, cc = t & 255;
        Wl[t] = (cc < 128) ? Wm1[k * 128 + cc] : Wm1[(64 + k) * 128 + (cc - 128)];
    }
    __syncthreads();
    int wv = threadIdx.x >> 6, lane = threadIdx.x & 63;
    int cc = lane * 4;
    float4 bias;
    if (lane < 32) bias = *(const float4*)&bm1[cc];
    else bias = make_float4(0.f, 0.f, 0.f, 0.f);
    int ngroups = (N + 7) >> 3;
    for (int g = blockIdx.x * 8 + wv; g < ngroups; g += gridDim.x * 8) {
        int base = rfl(g) * 8;
        const float* xp[8];
#pragma unroll
        for (int t = 0; t < 8; t++) {
            int d = base + t; if (d > N - 1) d = N - 1;
            xp[t] = xh + (size_t)d * 64;
        }
        float4 acc[8];
#pragma unroll
        for (int t = 0; t < 8; t++) acc[t] = bias;
#pragma unroll 2
        for (int k4 = 0; k4 < 16; k4++) {
            int k = k4 * 4;
            float4 xv4[8];
#pragma unroll
            for (int t = 0; t < 8; t++) xv4[t] = *(const float4*)&xp[t][k];
#pragma unroll
            for (int kk = 0; kk < 4; kk++) {
                float4 w = *(const float4*)&Wl[(k + kk) * 256 + cc];
#pragma unroll
                for (int t = 0; t < 8; t++) {
                    float xv = kk == 0 ? xv4[t].x : kk == 1 ? xv4[t].y : kk == 2 ? xv4[t].z : xv4[t].w;
                    acc[t].x += xv * w.x; acc[t].y += xv * w.y;
                    acc[t].z += xv * w.z; acc[t].w += xv * w.w;
                }
            }
        }
#pragma unroll
        for (int t = 0; t < 8; t++) {
            int d = base + t;
            if (d < N) {
                if (lane < 32) *(float4*)&Hb[(size_t)d * 128 + cc] = acc[t];
                else {
                    h4 o;
                    o[0] = (_Float16)acc[t].x; o[1] = (_Float16)acc[t].y;
                    o[2] = (_Float16)acc[t].z; o[3] = (_Float16)acc[t].w;
                    *(h4*)&PsH[(size_t)d * 128 + (cc - 128)] = o;
                }
            }
        }
    }
}

// ---------------- k_edge: fdot2, unroll 16/4/1; reads Pd f32, writes H fp16 ----------------
__global__ void __launch_bounds__(256)
k_edge(const _Float16* __restrict__ PsH, const _Float16* __restrict__ eap,
       const float* __restrict__ Wm1, const int* __restrict__ ptr,
       const int* __restrict__ slist, const float* __restrict__ Pd,
       _Float16* __restrict__ Hh, int N) {
    int c = threadIdx.x & 127;
    int half = threadIdx.x >> 7;
    h2 wh[8];
#pragma unroll
    for (int k = 0; k < 8; k++) {
        h2 t;
        t[0] = (_Float16)Wm1[128 * 128 + (2 * k) * 128 + c];
        t[1] = (_Float16)Wm1[128 * 128 + (2 * k + 1) * 128 + c];
        wh[k] = t;
    }
    for (int dd = blockIdx.x * 2 + half; dd < N; dd += gridDim.x * 2) {
        int d = rfl(dd);
        float pd = Pd[(size_t)d * 128 + c];
        int eb = rfl(ptr[d]), ee = rfl(ptr[d + 1]);
        const int* sp = slist + eb;
        const _Float16* ep = eap + (size_t)eb * EDIM;
        int ne = ee - eb;
        float acc = 0.f;
        int i = 0;
        for (; i + 16 <= ne; i += 16) {
            int ns[16];
#pragma unroll
            for (int j = 0; j < 16; j++) ns[j] = rfl(sp[i + j]);
            float pv[16];
#pragma unroll
            for (int j = 0; j < 16; j++) pv[j] = (float)PsH[(size_t)ns[j] * 128 + c];
#pragma unroll
            for (int j = 0; j < 16; j++) {
                union { uint4 u; h2 h[4]; } A, B;
                A.u = *(const uint4*)(ep + (size_t)(i + j) * EDIM);
                B.u = *(const uint4*)(ep + (size_t)(i + j) * EDIM + 8);
                float pe = 0.f;
#pragma unroll
                for (int k = 0; k < 4; k++) pe = __builtin_amdgcn_fdot2(A.h[k], wh[k], pe, false);
#pragma unroll
                for (int k = 0; k < 4; k++) pe = __builtin_amdgcn_fdot2(B.h[k], wh[4 + k], pe, false);
                acc += fmaxf(pd + pv[j] + pe, 0.f);
            }
        }
        for (; i + 4 <= ne; i += 4) {
            int ns[4];
#pragma unroll
            for (int j = 0; j < 4; j++) ns[j] = rfl(sp[i + j]);
            float pv[4];
#pragma unroll
            for (int j = 0; j < 4; j++) pv[j] = (float)PsH[(size_t)ns[j] * 128 + c];
#pragma unroll
            for (int j = 0; j < 4; j++) {
                union { uint4 u; h2 h[4]; } A, B;
                A.u = *(const uint4*)(ep + (size_t)(i + j) * EDIM);
                B.u = *(const uint4*)(ep + (size_t)(i + j) * EDIM + 8);
                float pe = 0.f;
#pragma unroll
                for (int k = 0; k < 4; k++) pe = __builtin_amdgcn_fdot2(A.h[k], wh[k], pe, false);
#pragma unroll
                for (int k = 0; k < 4; k++) pe = __builtin_amdgcn_fdot2(B.h[k], wh[4 + k], pe, false);
                acc += fmaxf(pd + pv[j] + pe, 0.f);
            }
        }
        for (; i < ne; i++) {
            int n0 = rfl(sp[i]);
            float pv = (float)PsH[(size_t)n0 * 128 + c];
            union { uint4 u; h2 h[4]; } A, B;
            A.u = *(const uint4*)(ep + (size_t)i * EDIM);
            B.u = *(const uint4*)(ep + (size_t)i * EDIM + 8);
            float pe = 0.f;
#pragma unroll
            for (int k = 0; k < 4; k++) pe = __builtin_amdgcn_fdot2(A.h[k], wh[k], pe, false);
#pragma unroll
            for (int k = 0; k < 4; k++) pe = __builtin_amdgcn_fdot2(B.h[k], wh[4 + k], pe, false);
            acc += fmaxf(pd + pv + pe, 0.f);
        }
        Hh[(size_t)d * 128 + c] = (_Float16)acc;
    }
}

// ---------------- k_node: fused GRU, fp16 activations via uniform uint4 loads ----------------
__global__ void __launch_bounds__(1024)
k_node(const _Float16* __restrict__ Hh, const uint4* __restrict__ gGA, const uint2* __restrict__ gGB,
       const uint4* __restrict__ gUA, const uint2* __restrict__ gUB,
       const float* __restrict__ gbb, const float* __restrict__ bih, const float* __restrict__ bhh,
       const int* __restrict__ ptr, const float* __restrict__ xin,
       const _Float16* __restrict__ xin16, float* __restrict__ xout,
       _Float16* __restrict__ xout16, int N) {
    extern __shared__ char smem[];
    uint4* GA = (uint4*)smem;              // 32 KB
    uint2* GB = (uint2*)(smem + 32768);    // 16 KB
    uint4* UA = (uint4*)(smem + 49152);    // 16 KB
    uint2* UB = (uint2*)(smem + 65536);    //  8 KB
    for (int t = threadIdx.x; t < 2048; t += 1024) { GA[t] = gGA[t]; GB[t] = gGB[t]; }
    for (int t = threadIdx.x; t < 1024; t += 1024) { UA[t] = gUA[t]; UB[t] = gUB[t]; }
    __syncthreads();
    int wv = threadIdx.x >> 6, lane = threadIdx.x & 63;
    float gbr = gbb[lane], gbz = gbb[64 + lane], gbn = gbb[128 + lane];
    float br = bih[lane], bz = bih[64 + lane], bn = bih[128 + lane];
    float cr = bhh[lane], cz = bhh[64 + lane], cn = bhh[128 + lane];
    int ngroups = (N + 3) >> 2;
    for (int g = blockIdx.x * 16 + wv; g < ngroups; g += gridDim.x * 16) {
        int base = rfl(g) * 4;
        const _Float16* hp16[4]; const _Float16* xp16[4]; const float* xp[4]; float deg[4];
#pragma unroll
        for (int t = 0; t < 4; t++) {
            int d = base + t; if (d > N - 1) d = N - 1;
            hp16[t] = Hh + (size_t)d * 128;
            xp16[t] = xin16 + (size_t)d * 64;
            xp[t] = xin + (size_t)d * 64;
            deg[t] = (float)(ptr[d + 1] - ptr[d]);
        }
        float gr[4], gz[4], gn[4];
#pragma unroll
        for (int t = 0; t < 4; t++) {
            gr[t] = br + deg[t] * gbr;
            gz[t] = bz + deg[t] * gbz;
            gn[t] = bn + deg[t] * gbn;
        }
        // H-side: K=128 -> 16 k8-iterations
#pragma unroll 2
        for (int k8 = 0; k8 < 16; k8++) {
            uint4 wa0 = GA[(2 * k8) * 64 + lane];
            uint2 wb0 = GB[(2 * k8) * 64 + lane];
            uint4 wa1 = GA[(2 * k8 + 1) * 64 + lane];
            uint2 wb1 = GB[(2 * k8 + 1) * 64 + lane];
#pragma unroll
            for (int t = 0; t < 4; t++) {
                uint4 a = *(const uint4*)(hp16[t] + k8 * 8);
                gr[t] = fdot2_(bh2(a.x), wa0.x, gr[t]); gz[t] = fdot2_(bh2(a.x), wa0.y, gz[t]);
                gn[t] = fdot2_(bh2(a.x), wa0.z, gn[t]);
                gr[t] = fdot2_(bh2(a.y), wa0.w, gr[t]); gz[t] = fdot2_(bh2(a.y), wb0.x, gz[t]);
                gn[t] = fdot2_(bh2(a.y), wb0.y, gn[t]);
                gr[t] = fdot2_(bh2(a.z), wa1.x, gr[t]); gz[t] = fdot2_(bh2(a.z), wa1.y, gz[t]);
                gn[t] = fdot2_(bh2(a.z), wa1.z, gn[t]);
                gr[t] = fdot2_(bh2(a.w), wa1.w, gr[t]); gz[t] = fdot2_(bh2(a.w), wb1.x, gz[t]);
                gn[t] = fdot2_(bh2(a.w), wb1.y, gn[t]);
            }
        }
        // U-side: K=64 -> 8 k8-iterations
        float hr[4], hz[4], hn[4], hv[4];
#pragma unroll
        for (int t = 0; t < 4; t++) { hr[t] = cr; hz[t] = cz; hn[t] = cn; hv[t] = xp[t][lane]; }
#pragma unroll 2
        for (int k8 = 0; k8 < 8; k8++) {
            uint4 wa0 = UA[(2 * k8) * 64 + lane];
            uint2 wb0 = UB[(2 * k8) * 64 + lane];
            uint4 wa1 = UA[(2 * k8 + 1) * 64 + lane];
            uint2 wb1 = UB[(2 * k8 + 1) * 64 + lane];
#pragma unroll
            for (int t = 0; t < 4; t++) {
                uint4 a = *(const uint4*)(xp16[t] + k8 * 8);
                hr[t] = fdot2_(bh2(a.x), wa0.x, hr[t]); hz[t] = fdot2_(bh2(a.x), wa0.y, hz[t]);
                hn[t] = fdot2_(bh2(a.x), wa0.z, hn[t]);
                hr[t] = fdot2_(bh2(a.y), wa0.w, hr[t]); hz[t] = fdot2_(bh2(a.y), wb0.x, hz[t]);
                hn[t] = fdot2_(bh2(a.y), wb0.y, hn[t]);
                hr[t] = fdot2_(bh2(a.z), wa1.x, hr[t]); hz[t] = fdot2_(bh2(a.z), wa1.y, hz[t]);
                hn[t] = fdot2_(bh2(a.z), wa1.z, hn[t]);
                hr[t] = fdot2_(bh2(a.w), wa1.w, hr[t]); hz[t] = fdot2_(bh2(a.w), wb1.x, hz[t]);
                hn[t] = fdot2_(bh2(a.w), wb1.y, hn[t]);
            }
        }
#pragma unroll
        for (int t = 0; t < 4; t++) {
            int d = base + t;
            if (d < N) {
                float r = sigm(gr[t] + hr[t]);
                float z = sigm(gz[t] + hz[t]);
                float nn = tanhf(gn[t] + r * hn[t]);
                float h = (1.f - z) * nn + z * hv[t];
                xout[(size_t)d * 64 + lane] = h;
                xout16[(size_t)d * 64 + lane] = (_Float16)h;
            }
        }
    }
}

// ---------------- fused Set2Set ----------------
__global__ void __launch_bounds__(1024)
k_s2s(const float* __restrict__ xh, const int* __restrict__ gptr,
      const float* __restrict__ WT1, const float* __restrict__ WT2,
      const float* __restrict__ lbih, const float* __restrict__ lbhh,
      const float* __restrict__ Wr1, const float* __restrict__ br1,
      const float* __restrict__ Wr2, const float* __restrict__ br2,
      float* __restrict__ out) {
    int b = blockIdx.x, tid = threadIdx.x;
    __shared__ float xl[SCAP * 64];
    __shared__ float qs[128], qhl[64], qcs[64], g[256], red[16], asums[16], rvs[1024];
    int start = gptr[b], end = gptr[b + 1];
    int seg = end - start;
    bool uselds = (seg <= SCAP);
    if (uselds) {
        int tot = seg * 64;
        for (int t = tid; t < tot; t += 1024) xl[t] = xh[(size_t)start * 64 + t];
    }
    if (tid < 128) qs[tid] = 0.f;
    if (tid < 64) { qhl[tid] = 0.f; qcs[tid] = 0.f; }
    __syncthreads();
    int grp = tid >> 6, lane = tid & 63;
    int gate = tid & 255, part = tid >> 8;
    for (int s = 0; s < 6; s++) {
        {
            float acc = 0.f;
            int k0 = part * 32;
#pragma unroll 8
            for (int k = k0; k < k0 + 32; k++) acc += qs[k] * WT1[k * 256 + gate];
            int k1 = part * 16;
#pragma unroll 8
            for (int k = k1; k < k1 + 16; k++) acc += qhl[k] * WT2[k * 256 + gate];
            rvs[tid] = acc;
        }
        __syncthreads();
        if (tid < 256) g[tid] = lbih[tid] + lbhh[tid] + rvs[tid] + rvs[256 + tid] + rvs[512 + tid] + rvs[768 + tid];
        __syncthreads();
        if (tid < 64) {
            float ig = sigm(g[tid]), fg = sigm(g[64 + tid]);
            float gg = tanhf(g[128 + tid]), og = sigm(g[192 + tid]);
            float c = fg * qcs[tid] + ig * gg;
            float h = og * tanhf(c);
            qcs[tid] = c; qhl[tid] = h; qs[tid] = h;
        }
        __syncthreads();
        float qv = qhl[lane];
        float mloc = -3.4e38f, asl = 0.f, rv = 0.f;
        for (int n = grp; n < seg; n += 16) {
            float xv = uselds ? xl[n * 64 + lane] : xh[(size_t)(start + n) * 64 + lane];
            float p = xv * qv;
#pragma unroll
            for (int off = 32; off > 0; off >>= 1) p += __shfl_xor(p, off);
            float mnew = fmaxf(mloc, p);
            float corr = expf(mloc - mnew);
            float a = expf(p - mnew);
            asl = asl * corr + a;
            rv = rv * corr + a * xv;
            mloc = mnew;
        }
        if (lane == 0) red[grp] = mloc;
        __syncthreads();
        float gmax = red[0];
#pragma unroll
        for (int j = 1; j < 16; j++) gmax = fmaxf(gmax, red[j]);
        float sc = expf(mloc - gmax);
        rvs[tid] = rv * sc;
        if (lane == 0) asums[grp] = asl * sc;
        __syncthreads();
        if (tid < 64) {
            float rt = 0.f, at = 0.f;
#pragma unroll
            for (int j = 0; j < 16; j++) { rt += rvs[tid + 64 * j]; at += asums[j]; }
            qs[64 + tid] = (at > 0.f) ? rt / at : 0.f;
        }
        __syncthreads();
    }
    if (tid < 64) {
        float a2 = br1[tid];
#pragma unroll 8
        for (int k = 0; k < 128; k++) a2 += qs[k] * Wr1[k * 64 + tid];
        a2 = fmaxf(a2, 0.f);
        float v = a2 * Wr2[tid];
#pragma unroll
        for (int off = 32; off > 0; off >>= 1) v += __shfl_xor(v, off);
        if (tid == 0) out[b] = v + br2[0];
    }
}

extern "C" void kernel_launch(void* const* d_in, const int* in_sizes, int n_in,
                              void* d_out, int out_size, void* d_ws, size_t ws_size,
                              hipStream_t stream) {
    const float* x_feat = (const float*)d_in[0];
    const int*   ei     = (const int*)d_in[1];
    const float* eattr  = (const float*)d_in[2];
    const int*   batch  = (const int*)d_in[3];
    const float* W_emb  = (const float*)d_in[4];
    const float* b_emb  = (const float*)d_in[5];
    const float* W_m1   = (const float*)d_in[6];
    const float* b_m1   = (const float*)d_in[7];
    const float* W_m2   = (const float*)d_in[8];
    const float* b_m2   = (const float*)d_in[9];
    const float* gWih   = (const float*)d_in[10];
    const float* gWhh   = (const float*)d_in[11];
    const float* gbih   = (const float*)d_in[12];
    const float* gbhh   = (const float*)d_in[13];
    const float* lWih   = (const float*)d_in[14];
    const float* lWhh   = (const float*)d_in[15];
    const float* lbih   = (const float*)d_in[16];
    const float* lbhh   = (const float*)d_in[17];
    const float* Wr1    = (const float*)d_in[18];
    const float* br1    = (const float*)d_in[19];
    const float* Wr2    = (const float*)d_in[20];
    const float* br2    = (const float*)d_in[21];

    int N = in_sizes[0] / NDIM;   // 50000
    int E = in_sizes[1] / 2;      // 800000

    char* w = (char*)d_ws;
    auto alloc = [&](size_t b) { char* p = w; w += (b + 511) & ~(size_t)511; return p; };
    float*     xh    = (float*)alloc((size_t)N * 64 * 4);
    float*     xh2   = (float*)alloc((size_t)N * 64 * 4);
    _Float16*  xh16a = (_Float16*)alloc((size_t)N * 64 * 2);
    _Float16*  xh16b = (_Float16*)alloc((size_t)N * 64 * 2);
    _Float16*  PsH   = (_Float16*)alloc((size_t)N * 128 * 2);
    float*     Hb    = (float*)alloc((size_t)N * 128 * 4);
    _Float16*  Hh    = (_Float16*)alloc((size_t)N * 128 * 2);
    int*       ptr   = (int*)alloc((size_t)(N + 1) * 4);
    int*       slist = (int*)alloc((size_t)E * 4);
    _Float16*  eap   = (_Float16*)alloc((size_t)E * EDIM * 2);
    uint4*     gGA   = (uint4*)alloc((size_t)2048 * 16);
    uint2*     gGB   = (uint2*)alloc((size_t)2048 * 8);
    uint4*     gUA   = (uint4*)alloc((size_t)1024 * 16);
    uint2*     gUB   = (uint2*)alloc((size_t)1024 * 8);
    float*     gbb   = (float*)alloc((size_t)192 * 4);
    float*     WT1   = (float*)alloc((size_t)128 * 256 * 4);
    float*     WT2   = (float*)alloc((size_t)64 * 256 * 4);
    int*       gptr  = (int*)alloc((size_t)(NG + 1) * 4);
    int*       bsum  = (int*)alloc(128 * 4);
    int*       boff  = (int*)alloc(128 * 4);
    char* z0 = w;
    int*       cnt    = (int*)alloc((size_t)N * 4);
    int*       cursor = (int*)alloc((size_t)N * 4);
    char* z0e = w;

    hipMemsetAsync(z0, 0, (size_t)(z0e - z0), stream);

    hipError_t attr_err = hipFuncSetAttribute((const void*)k_node,
        hipFuncAttributeMaxDynamicSharedMemorySize, 73728);
    (void)attr_err;

    int NB = (N + 1023) / 1024;
    k_hist<<<1024, 256, 0, stream>>>(ei + E, E, cnt);
    k_scanA<<<NB, 1024, 0, stream>>>(cnt, ptr, bsum, N);
    k_scanB<<<1, 64, 0, stream>>>(bsum, boff, NB);
    k_scanC<<<(N + 256) / 256, 256, 0, stream>>>(ptr, boff, N, NB);
    k_gptr<<<3, 256, 0, stream>>>(batch, N, gptr);
    k_scatter<<<3125, 256, 0, stream>>>(ei, ei + E, eattr, E, ptr, cursor, slist, eap);
    k_fuse<<<13, 256, 0, stream>>>(gWih, gWhh, W_m2, b_m2, gGA, gGB, gUA, gUB, gbb);
    k_packl<<<128, 256, 0, stream>>>(lWih, lWhh, WT1, WT2);

    k_embed<<<2048, 256, 0, stream>>>(x_feat, W_emb, b_emb, xh, xh16a, N);

    float* xa = xh;       float* xb = xh2;
    _Float16* xa16 = xh16a; _Float16* xb16 = xh16b;
    for (int r = 0; r < 3; r++) {
        k_prep<<<196, 512, 0, stream>>>(xa, W_m1, b_m1, Hb, PsH, N);
        k_edge<<<4096, 256, 0, stream>>>(PsH, eap, W_m1, ptr, slist, Hb, Hh, N);
        k_node<<<256, 1024, 73728, stream>>>(Hh, gGA, gGB, gUA, gUB, gbb, gbih, gbhh,
                                             ptr, xa, xa16, xb, xb16, N);
        float* t = xa; xa = xb; xb = t;
        _Float16* t16 = xa16; xa16 = xb16; xb16 = t16;
    }
    k_s2s<<<NG, 1024, 0, stream>>>(xa, gptr, WT1, WT2, lbih, lbhh,
                                   Wr1, br1, Wr2, br2, (float*)d_out);
}